// Round 10
// baseline (143.727 us; speedup 1.0000x reference)
//
#include <hip/hip_runtime.h>

// workspace layout (float offsets)
#define OFF_X1  0            // conv1 out: GN'd+ReLU'd fp32 [b][c][n], 1M floats
#define OFF_SA  1048576      // fallback sa fp32, 1M floats
#define OFF_QT  2097152      // q bf16 [b][n][32] (1 MB)
#define OFF_KT  2359296      // k bf16 [b][n][32]
#define OFF_VB  2621440      // v bf16 [b][c][n] (2 MB)
#define OFF_YT  3145728      // y bf16 [b][n][ci] (2 MB)
#define OFF_XB  3670016      // x bf16 [b][n][ci] (2 MB)
#define OFF_AC  4194304      // gram accumulator fp32 [b][c][d] (64 KB, zeroed by cvt)
#define OFF_WBI 4210688
#define OFF_WBO 4265984
#define OFF_PT  4321280      // GN sums: pt0[32], pt1[32], cnt0, cnt1
#define OFF_PO  4325376      // split-flash acc partials bf16: 1024 x 4096 (8 MB)
#define OFF_MS  6422528      // split-flash (M,S): 1024 x 128 f32
#define WS_NEED ((size_t)6553600 * 4)

typedef __attribute__((ext_vector_type(8))) short short8v;
typedef __attribute__((ext_vector_type(4))) short short4v;
typedef __attribute__((ext_vector_type(4))) float f32x4;

__device__ __forceinline__ ushort f2bf(float f) {
  union { float f; unsigned u; } v; v.f = f;
  unsigned r = (v.u + 0x7fffu + ((v.u >> 16) & 1u)) >> 16;
  return (ushort)r;
}
__device__ __forceinline__ float bf2f(ushort u) {
  union { unsigned u; float f; } v; v.u = ((unsigned)u) << 16;
  return v.f;
}
__device__ __forceinline__ float max3f(float a, float b, float c) {
  return fmaxf(fmaxf(a, b), c);
}

// ---- merged converts: x transpose (0..255), weights (256..1119), zero ac+pt+cnt (1120..1183) ----
__global__ __launch_bounds__(256) void cvt_k(const float* __restrict__ x, ushort* __restrict__ xb,
    float* __restrict__ pt, const float* __restrict__ wi, const float* __restrict__ wo,
    ushort* __restrict__ wbi, ushort* __restrict__ wbo, float* __restrict__ acr) {
  __shared__ ushort tl[64 * 72];
  int blk = blockIdx.x;
  int t = threadIdx.x;
  if (blk < 256) {
    int b = blk >> 6;
    int n0 = (blk & 63) * 64;
    int ci = t >> 2, q = t & 3;
    const float* src = x + (size_t)(b * 64 + ci) * 4096 + n0 + q * 16;
    #pragma unroll
    for (int i = 0; i < 4; ++i) {
      float4 v = *reinterpret_cast<const float4*>(src + i * 4);
      tl[(q * 16 + i * 4 + 0) * 72 + ci] = f2bf(v.x);
      tl[(q * 16 + i * 4 + 1) * 72 + ci] = f2bf(v.y);
      tl[(q * 16 + i * 4 + 2) * 72 + ci] = f2bf(v.z);
      tl[(q * 16 + i * 4 + 3) * 72 + ci] = f2bf(v.w);
    }
    __syncthreads();
    int n = t >> 2, qq = t & 3;
    ushort* dst = xb + (size_t)(b * 4096 + n0 + n) * 64 + qq * 16;
    *reinterpret_cast<short8v*>(dst) = *reinterpret_cast<const short8v*>(&tl[n * 72 + qq * 16]);
    *reinterpret_cast<short8v*>(dst + 8) = *reinterpret_cast<const short8v*>(&tl[n * 72 + qq * 16 + 8]);
  } else if (blk < 1120) {
    int idx = (blk - 256) * 256 + t;       // 0 .. 221183
    const float* w = idx < 110592 ? wi : wo;
    ushort* wb = idx < 110592 ? wbi : wbo;
    int j = idx < 110592 ? idx : idx - 110592;
    int ci = j & 63, tap = (j >> 6) % 27, co = j / (64 * 27);
    wb[j] = f2bf(w[(co * 64 + ci) * 27 + tap]);
  } else {
    int idx = (blk - 1120) * 256 + t;      // 0 .. 16383
    acr[idx] = 0.f;
    if (blk == 1120 && t < 128) pt[t] = 0.f;   // pt0[32], pt1[32], cnt0, cnt1, pad
  }
}

// ------- conv3d implicit GEMM + grid-sync GroupNorm + ReLU epilogue -> fp32 [b][c][n] -------
__global__ __launch_bounds__(256) void conv_mfma_k(const ushort* __restrict__ xt,
    const ushort* __restrict__ wb, const float* __restrict__ bias,
    const float* __restrict__ gamma, const float* __restrict__ beta,
    float* __restrict__ ptg, unsigned* __restrict__ cnt, float* __restrict__ out) {
  __shared__ __align__(16) ushort xls[18 * 18 * 64];
  __shared__ float sh_st[16];
  int blk = blockIdx.x;
  int h0 = (blk & 3) * 4;
  int d0 = (blk >> 2) & 15;
  int b  = blk >> 6;
  int tid = threadIdx.x;

  const ushort* xtb = xt + (size_t)b * 4096 * 64;
  for (int u = tid; u < 324; u += 256) {
    int w_s = u % 18;
    int row = u / 18;
    int dz = row / 6, h_s = row - dz * 6;
    int d = d0 + dz - 1, h = h0 + h_s - 1, w = w_s - 1;
    ushort* dst = &xls[(row * 18 + w_s) * 64];
    int swz = w_s & 7;
    if (d >= 0 && d < 16 && h >= 0 && h < 16 && w >= 0 && w < 16) {
      const ushort* src = xtb + (size_t)(d * 256 + h * 16 + w) * 64;
      #pragma unroll
      for (int c = 0; c < 8; ++c)
        *reinterpret_cast<short8v*>(dst + ((c ^ swz) << 3)) =
            *reinterpret_cast<const short8v*>(src + (c << 3));
    } else {
      short8v z = {};
      #pragma unroll
      for (int c = 0; c < 8; ++c)
        *reinterpret_cast<short8v*>(dst + ((c ^ swz) << 3)) = z;
    }
  }
  __syncthreads();

  int wv = tid >> 6, l = tid & 63;
  int wn = wv >> 1, wc = wv & 1;
  int lm = l & 15, lg = l >> 4;

  f32x4 acc[2][2] = {};
  const ushort* wbase0 = wb + (size_t)((wc * 2 + 0) * 16 + lm) * 1728 + lg * 8;
  const ushort* wbase1 = wb + (size_t)((wc * 2 + 1) * 16 + lm) * 1728 + lg * 8;

  #pragma unroll 6
  for (int s = 0; s < 54; ++s) {
    int tap = s >> 1, c0h = s & 1;
    int dz = tap / 9, dyx = tap - dz * 9;
    int dy = dyx / 3, dx = dyx - dy * 3;
    int wrow = lm + dx;
    int chunk = ((c0h * 4 + lg) ^ (wrow & 7)) << 3;
    int r0 = ((dz * 6 + wn * 2 + dy) * 18 + wrow) * 64 + chunk;
    short8v a0 = *reinterpret_cast<const short8v*>(&xls[r0]);
    short8v a1 = *reinterpret_cast<const short8v*>(&xls[r0 + 18 * 64]);
    short8v b0 = *reinterpret_cast<const short8v*>(wbase0 + s * 32);
    short8v b1 = *reinterpret_cast<const short8v*>(wbase1 + s * 32);
    acc[0][0] = __builtin_amdgcn_mfma_f32_16x16x32_bf16(a0, b0, acc[0][0], 0, 0, 0);
    acc[0][1] = __builtin_amdgcn_mfma_f32_16x16x32_bf16(a0, b1, acc[0][1], 0, 0, 0);
    acc[1][0] = __builtin_amdgcn_mfma_f32_16x16x32_bf16(a1, b0, acc[1][0], 0, 0, 0);
    acc[1][1] = __builtin_amdgcn_mfma_f32_16x16x32_bf16(a1, b1, acc[1][1], 0, 0, 0);
  }

  // add bias in place; accumulate block stats
  float gs[2], gss[2];
  #pragma unroll
  for (int j = 0; j < 2; ++j) {
    gs[j] = 0.f; gss[j] = 0.f;
    int co = (wc * 2 + j) * 16 + lm;
    float bs = bias[co];
    #pragma unroll
    for (int i = 0; i < 2; ++i)
      #pragma unroll
      for (int r = 0; r < 4; ++r) {
        float o = acc[i][j][r] + bs;
        acc[i][j][r] = o;
        gs[j] += o;
        gss[j] = fmaf(o, o, gss[j]);
      }
  }
  #pragma unroll
  for (int j = 0; j < 2; ++j) {
    #pragma unroll
    for (int off = 32; off > 0; off >>= 1) {
      gs[j]  += __shfl_xor(gs[j], off);
      gss[j] += __shfl_xor(gss[j], off);
    }
    if (l == 0) { sh_st[wv * 4 + j * 2] = gs[j]; sh_st[wv * 4 + j * 2 + 1] = gss[j]; }
  }
  __syncthreads();
  if (tid < 8) {
    int g = tid >> 1, w2 = tid & 1;
    int wcg = g >> 1, j = g & 1;
    float v = sh_st[wcg * 4 + j * 2 + w2] + sh_st[(wcg + 2) * 4 + j * 2 + w2];
    atomicAdd(&ptg[(b * 4 + g) * 2 + w2], v);
  }
  __syncthreads();
  // grid barrier: all 256 blocks co-resident (1 block/CU)
  if (tid == 0) {
    __threadfence();
    __hip_atomic_fetch_add(cnt, 1u, __ATOMIC_ACQ_REL, __HIP_MEMORY_SCOPE_AGENT);
    while (__hip_atomic_load(cnt, __ATOMIC_ACQUIRE, __HIP_MEMORY_SCOPE_AGENT) < 256u) {
      __builtin_amdgcn_s_sleep(2);
    }
  }
  __syncthreads();
  // normalize + relu + store
  #pragma unroll
  for (int j = 0; j < 2; ++j) {
    int g = wc * 2 + j;
    float s0  = __hip_atomic_load(&ptg[(b * 4 + g) * 2],     __ATOMIC_RELAXED, __HIP_MEMORY_SCOPE_AGENT);
    float ss0 = __hip_atomic_load(&ptg[(b * 4 + g) * 2 + 1], __ATOMIC_RELAXED, __HIP_MEMORY_SCOPE_AGENT);
    float m = s0 * (1.f / 65536.f);
    float rv = rsqrtf(ss0 * (1.f / 65536.f) - m * m + 1e-5f);
    int co = g * 16 + lm;
    float ga = rv * gamma[co], bb2 = beta[co] - m * rv * gamma[co];
    #pragma unroll
    for (int i = 0; i < 2; ++i) {
      int hh = h0 + wn * 2 + i;
      float4 o;
      o.x = fmaxf(fmaf(acc[i][j][0], ga, bb2), 0.f);
      o.y = fmaxf(fmaf(acc[i][j][1], ga, bb2), 0.f);
      o.z = fmaxf(fmaf(acc[i][j][2], ga, bb2), 0.f);
      o.w = fmaxf(fmaf(acc[i][j][3], ga, bb2), 0.f);
      *reinterpret_cast<float4*>(&out[(size_t)(b * 64 + co) * 4096 + d0 * 256 + hh * 16 + lg * 4]) = o;
    }
  }
}

// ---------------- merged proj (blocks 0..255) + gram partial w/ atomics (256..383) ----------------
__global__ __launch_bounds__(256) void projgram_k(const float* __restrict__ x1,
    const float* __restrict__ wq, const float* __restrict__ bq,
    const float* __restrict__ wk, const float* __restrict__ bk,
    const float* __restrict__ wv_, const float* __restrict__ bv,
    ushort* __restrict__ qt, ushort* __restrict__ kt, ushort* __restrict__ vt,
    float* __restrict__ acr) {
  __shared__ __align__(16) float smem[64 * 68];
  int blk = blockIdx.x;
  int tid = threadIdx.x;
  if (blk < 256) {
    // ---- projection (x1 already GN'd+ReLU'd) ----
    float* xls = smem;
    int b = blk >> 6, n0 = (blk & 63) * 64;
    {
      int ci = tid >> 2, q = tid & 3;
      const float* src = x1 + (size_t)(b * 64 + ci) * 4096 + n0 + q * 16;
      #pragma unroll
      for (int i = 0; i < 4; ++i) {
        float4 v = *reinterpret_cast<const float4*>(src + i * 4);
        float* d = &xls[ci * 68 + q * 16 + i * 4];
        d[0] = v.x; d[1] = v.y; d[2] = v.z; d[3] = v.w;
      }
    }
    __syncthreads();
    int n = tid & 63, og = tid >> 6;
    float xr[64];
    #pragma unroll
    for (int c = 0; c < 64; ++c) xr[c] = xls[c * 68 + n];
    if (og < 2) {
      const float* w  = og == 0 ? wq : wk;
      const float* bb = og == 0 ? bq : bk;
      float scale = og == 0 ? 1.4426950408889634f : 1.0f;
      ushort* outp = og == 0 ? qt : kt;
      union { ushort u[16]; short8v v[2]; } pk;
      #pragma unroll
      for (int o = 0; o < 16; ++o) {
        const float* wr = w + o * 64;
        float acc = bb[o];
        #pragma unroll
        for (int c = 0; c < 64; ++c) acc = fmaf(wr[c], xr[c], acc);
        pk.u[o] = f2bf(acc * scale);
      }
      ushort* dst = outp + (size_t)(b * 4096 + n0 + n) * 32;
      *reinterpret_cast<short8v*>(dst) = pk.v[0];
      *reinterpret_cast<short8v*>(dst + 8) = pk.v[1];
      short8v z = {};
      *reinterpret_cast<short8v*>(dst + 16) = z;
      *reinterpret_cast<short8v*>(dst + 24) = z;
    } else {
      int o0 = (og - 2) * 32;
      #pragma unroll
      for (int o = 0; o < 32; ++o) {
        const float* wr = wv_ + (o0 + o) * 64;
        float acc = bv[o0 + o];
        #pragma unroll
        for (int c = 0; c < 64; ++c) acc = fmaf(wr[c], xr[c], acc);
        vt[(size_t)(b * 64 + o0 + o) * 4096 + n0 + n] = f2bf(acc);
      }
    }
  } else {
    // ---- gram partial (hi/lo bf16 MFMA) -> atomicAdd into acr ----
    ushort* hi = (ushort*)smem;
    ushort* lo = hi + 4096;
    int gblk = blk - 256;
    int b = gblk >> 5, ks = gblk & 31;
    int wv = tid >> 6, l = tid & 63, lm = l & 15, lg = l >> 4;
    int wr = wv >> 1, wd = wv & 1;
    f32x4 acc[2][2] = {};
    int sr = tid >> 2, sq = tid & 3;
    const float* xb = x1 + (size_t)b * 262144;

    for (int kt2 = 0; kt2 < 2; ++kt2) {
      int n0 = ks * 128 + kt2 * 64;
      __syncthreads();
      const float* src = xb + (size_t)sr * 4096 + n0 + sq * 16;
      #pragma unroll
      for (int c2 = 0; c2 < 2; ++c2) {
        int chunk = sq * 2 + c2;
        int dchunk = chunk ^ (sr & 7);
        short8v hvv, lvv;
        #pragma unroll
        for (int j = 0; j < 8; ++j) {
          float v = src[c2 * 8 + j];
          ushort hb = f2bf(v);
          union { float f; unsigned u; } uu; uu.u = ((unsigned)hb) << 16;
          hvv[j] = (short)hb;
          lvv[j] = (short)f2bf(v - uu.f);
        }
        *reinterpret_cast<short8v*>(hi + sr * 64 + dchunk * 8) = hvv;
        *reinterpret_cast<short8v*>(lo + sr * 64 + dchunk * 8) = lvv;
      }
      __syncthreads();
      #pragma unroll
      for (int kk = 0; kk < 2; ++kk) {
        short8v ah[2], al[2], bh[2], bl[2];
        #pragma unroll
        for (int i = 0; i < 2; ++i) {
          int rc = wr * 32 + i * 16 + lm;
          int ca = ((kk * 4 + lg) ^ (rc & 7)) * 8;
          ah[i] = *reinterpret_cast<const short8v*>(hi + rc * 64 + ca);
          al[i] = *reinterpret_cast<const short8v*>(lo + rc * 64 + ca);
          int rd = wd * 32 + i * 16 + lm;
          int cb = ((kk * 4 + lg) ^ (rd & 7)) * 8;
          bh[i] = *reinterpret_cast<const short8v*>(hi + rd * 64 + cb);
          bl[i] = *reinterpret_cast<const short8v*>(lo + rd * 64 + cb);
        }
        #pragma unroll
        for (int i = 0; i < 2; ++i)
          #pragma unroll
          for (int j = 0; j < 2; ++j) {
            acc[i][j] = __builtin_amdgcn_mfma_f32_16x16x32_bf16(ah[i], bh[j], acc[i][j], 0, 0, 0);
            acc[i][j] = __builtin_amdgcn_mfma_f32_16x16x32_bf16(ah[i], bl[j], acc[i][j], 0, 0, 0);
            acc[i][j] = __builtin_amdgcn_mfma_f32_16x16x32_bf16(al[i], bh[j], acc[i][j], 0, 0, 0);
          }
      }
    }
    float* acb = acr + (size_t)b * 4096;
    #pragma unroll
    for (int i = 0; i < 2; ++i)
      #pragma unroll
      for (int j = 0; j < 2; ++j)
        #pragma unroll
        for (int r = 0; r < 4; ++r) {
          int c = wr * 32 + i * 16 + lg * 4 + r;
          int d = wd * 32 + j * 16 + lm;
          atomicAdd(&acb[c * 64 + d], acc[i][j][r]);
        }
  }
}

// ---------------- flash spatial attention, bf16 MFMA, double-buffered, optional split-K ----------------
#define KP 40
#define VP 72
template<bool SPLIT>
__global__ __launch_bounds__(256) void flash_mfma_k(const ushort* __restrict__ qt,
    const ushort* __restrict__ kt, const ushort* __restrict__ vb, float* __restrict__ sa,
    ushort* __restrict__ pacc, float* __restrict__ pms) {
  __shared__ __align__(16) ushort kls[2][64 * KP];
  __shared__ __align__(16) ushort vls[2][64 * VP];
  __shared__ __align__(16) ushort pls[64 * VP];
  int s, mt, b;
  if (SPLIT) { s = blockIdx.x & 3; mt = (blockIdx.x >> 2) & 63; b = blockIdx.x >> 8; }
  else       { s = 0; mt = blockIdx.x & 63; b = blockIdx.x >> 6; }
  const int NT = SPLIT ? 16 : 64;
  int m0 = mt * 64;
  int kofs = s * 1024;
  int tid = threadIdx.x;
  int w = tid >> 6, l = tid & 63;
  int lm = l & 15, lg = l >> 4;

  short8v qf = *reinterpret_cast<const short8v*>(
      qt + (size_t)(b * 4096 + m0 + w * 16 + lm) * 32 + lg * 8);

  f32x4 acc[4] = {};
  float M = -1e30f, S = 0.f;

  int sr = tid >> 2, sq = tid & 3;
  const ushort* ksrc = kt + (size_t)b * 4096 * 32 + (size_t)kofs * 32 + (size_t)sr * 32 + sq * 8;
  const ushort* vsrc = vb + (size_t)b * 64 * 4096 + (size_t)sr * 4096 + kofs + sq * 16;
  int koff = sr * KP + sq * 8;
  int voff = sr * VP + sq * 16;

  {
    short8v kr = *reinterpret_cast<const short8v*>(ksrc);
    short8v v0 = *reinterpret_cast<const short8v*>(vsrc);
    short8v v1 = *reinterpret_cast<const short8v*>(vsrc + 8);
    *reinterpret_cast<short8v*>(&kls[0][koff]) = kr;
    *reinterpret_cast<short8v*>(&vls[0][voff]) = v0;
    *reinterpret_cast<short8v*>(&vls[0][voff + 8]) = v1;
  }

  ushort* plb = &pls[(w * 16 + lm) * VP];

  #pragma unroll 2
  for (int it = 0; it < NT; ++it) {
    int cur = it & 1;
    int nx = it < NT - 1 ? it + 1 : NT - 1;
    short8v knr = *reinterpret_cast<const short8v*>(ksrc + (size_t)nx * 2048);
    short8v vn0 = *reinterpret_cast<const short8v*>(vsrc + nx * 64);
    short8v vn1 = *reinterpret_cast<const short8v*>(vsrc + nx * 64 + 8);

    __syncthreads();

    const ushort* kb  = &kls[cur][0];
    const ushort* vbk = &vls[cur][0];

    f32x4 sf[4];
    #pragma unroll
    for (int nt = 0; nt < 4; ++nt) {
      short8v kf = *reinterpret_cast<const short8v*>(&kb[(nt * 16 + lm) * KP + lg * 8]);
      f32x4 z = {};
      sf[nt] = __builtin_amdgcn_mfma_f32_16x16x32_bf16(kf, qf, z, 0, 0, 0);
    }

    float t0_ = max3f(sf[0][0], sf[0][1], sf[0][2]);
    float t1_ = max3f(sf[0][3], sf[1][0], sf[1][1]);
    float t2_ = max3f(sf[1][2], sf[1][3], sf[2][0]);
    float t3_ = max3f(sf[2][1], sf[2][2], sf[2][3]);
    float t4_ = max3f(sf[3][0], sf[3][1], sf[3][2]);
    float tmax = fmaxf(max3f(t0_, t1_, t2_), max3f(t3_, t4_, sf[3][3]));
    tmax = fmaxf(tmax, __shfl_xor(tmax, 16));
    tmax = fmaxf(tmax, __shfl_xor(tmax, 32));
    if (!__all(tmax <= M)) {
      float Mn = fmaxf(M, tmax);
      float sc = __builtin_amdgcn_exp2f(M - Mn);
      M = Mn;
      S *= sc;
      #pragma unroll
      for (int ct = 0; ct < 4; ++ct)
        #pragma unroll
        for (int r = 0; r < 4; ++r) acc[ct][r] *= sc;
    }
    float tsum = 0.f;
    float p[16];
    #pragma unroll
    for (int nt = 0; nt < 4; ++nt)
      #pragma unroll
      for (int r = 0; r < 4; ++r) {
        float e = __builtin_amdgcn_exp2f(sf[nt][r] - M);
        p[nt * 4 + r] = e;
        tsum += e;
      }
    tsum += __shfl_xor(tsum, 16);
    tsum += __shfl_xor(tsum, 32);
    S += tsum;

    #pragma unroll
    for (int nt = 0; nt < 4; ++nt) {
      unsigned p01, p23;
      asm("v_cvt_pk_bf16_f32 %0, %1, %2" : "=v"(p01) : "v"(p[nt * 4 + 0]), "v"(p[nt * 4 + 1]));
      asm("v_cvt_pk_bf16_f32 %0, %1, %2" : "=v"(p23) : "v"(p[nt * 4 + 2]), "v"(p[nt * 4 + 3]));
      union { unsigned u[2]; short4v v; } pk;
      pk.u[0] = p01; pk.u[1] = p23;
      *reinterpret_cast<short4v*>(plb + nt * 16 + lg * 4) = pk.v;
    }
    asm volatile("s_waitcnt lgkmcnt(0)" ::: "memory");
    __builtin_amdgcn_sched_barrier(0);

    #pragma unroll
    for (int nh = 0; nh < 2; ++nh) {
      short8v pf = *reinterpret_cast<const short8v*>(plb + nh * 32 + lg * 8);
      #pragma unroll
      for (int ct = 0; ct < 4; ++ct) {
        short8v vf = *reinterpret_cast<const short8v*>(&vbk[(ct * 16 + lm) * VP + nh * 32 + lg * 8]);
        acc[ct] = __builtin_amdgcn_mfma_f32_16x16x32_bf16(vf, pf, acc[ct], 0, 0, 0);
      }
    }

    if (it < NT - 1) {
      *reinterpret_cast<short8v*>(&kls[cur ^ 1][koff]) = knr;
      *reinterpret_cast<short8v*>(&vls[cur ^ 1][voff]) = vn0;
      *reinterpret_cast<short8v*>(&vls[cur ^ 1][voff + 8]) = vn1;
    }
  }

  if (SPLIT) {
    int blk2 = (b * 64 + mt) * 4 + s;
    ushort* pa = pacc + (size_t)blk2 * 4096;
    #pragma unroll
    for (int ct = 0; ct < 4; ++ct)
      #pragma unroll
      for (int r = 0; r < 4; ++r)
        pa[(ct * 16 + lg * 4 + r) * 64 + w * 16 + lm] = f2bf(acc[ct][r]);
    if (l < 16) {
      pms[(size_t)blk2 * 128 + (w * 16 + lm) * 2]     = M;
      pms[(size_t)blk2 * 128 + (w * 16 + lm) * 2 + 1] = S;
    }
  } else {
    float inv = 1.f / S;
    #pragma unroll
    for (int ct = 0; ct < 4; ++ct)
      #pragma unroll
      for (int r = 0; r < 4; ++r)
        sa[(size_t)(b * 64 + ct * 16 + lg * 4 + r) * 4096 + m0 + w * 16 + lm] = acc[ct][r] * inv;
  }
}

// ------- y = x1 + sa(+combine) + softmax(gram) @ x1 -> bf16 [b][n][ci]; softmax inline -------
template<int NSPLIT>
__global__ __launch_bounds__(256) void ca_apply_k(const float* __restrict__ x1,
    const float* __restrict__ acr, const float* __restrict__ sa,
    const ushort* __restrict__ pacc, const float* __restrict__ pms, ushort* __restrict__ yt) {
  __shared__ float x1f[64 * 72];
  __shared__ float acf[64 * 72];
  __shared__ float wls[4 * 64];
  int b = blockIdx.x >> 6, mt = blockIdx.x & 63;
  int n0 = mt * 64;
  int tid = threadIdx.x;
  {
    int d = tid >> 2, q = tid & 3;
    const float* xs = x1 + (size_t)(b * 64 + d) * 4096 + n0 + q * 16;
    const float* as = acr + (size_t)(b * 64 + d) * 64 + q * 16;
    #pragma unroll
    for (int i = 0; i < 4; ++i) {
      float4 v = *reinterpret_cast<const float4*>(xs + i * 4);
      x1f[d * 72 + q * 16 + i * 4 + 0] = v.x;
      x1f[d * 72 + q * 16 + i * 4 + 1] = v.y;
      x1f[d * 72 + q * 16 + i * 4 + 2] = v.z;
      x1f[d * 72 + q * 16 + i * 4 + 3] = v.w;
      float4 a = *reinterpret_cast<const float4*>(as + i * 4);
      acf[d * 72 + q * 16 + i * 4 + 0] = a.x;
      acf[d * 72 + q * 16 + i * 4 + 1] = a.y;
      acf[d * 72 + q * 16 + i * 4 + 2] = a.z;
      acf[d * 72 + q * 16 + i * 4 + 3] = a.w;
    }
  }
  if (NSPLIT > 1 && tid < 64) {
    int m = tid;
    size_t msb = (size_t)(b * 64 + mt) * NSPLIT * 128;
    float Ms[NSPLIT], Ss[NSPLIT];
    float Mg = -1e30f;
    #pragma unroll
    for (int s = 0; s < NSPLIT; ++s) {
      Ms[s] = pms[msb + s * 128 + m * 2];
      Ss[s] = pms[msb + s * 128 + m * 2 + 1];
      Mg = fmaxf(Mg, Ms[s]);
    }
    float Stot = 0.f;
    #pragma unroll
    for (int s = 0; s < NSPLIT; ++s) {
      float wv = __builtin_amdgcn_exp2f(Ms[s] - Mg);
      wls[s * 64 + m] = wv;
      Stot += wv * Ss[s];
    }
    float inv = 1.f / Stot;
    #pragma unroll
    for (int s = 0; s < NSPLIT; ++s) wls[s * 64 + m] *= inv;
  }
  __syncthreads();
  // in-place row softmax of acf (rows = c, over d)
  {
    int r = tid >> 2, q4 = tid & 3;
    float* row = &acf[r * 72 + q4 * 16];
    float mx = -1e30f;
    #pragma unroll
    for (int i = 0; i < 16; ++i) mx = fmaxf(mx, row[i]);
    mx = fmaxf(mx, __shfl_xor(mx, 1));
    mx = fmaxf(mx, __shfl_xor(mx, 2));
    float e[16];
    float sum = 0.f;
    #pragma unroll
    for (int i = 0; i < 16; ++i) { e[i] = __expf(row[i] - mx); sum += e[i]; }
    sum += __shfl_xor(sum, 1);
    sum += __shfl_xor(sum, 2);
    float inv = 1.f / sum;
    #pragma unroll
    for (int i = 0; i < 16; ++i) row[i] = e[i] * inv;
  }
  __syncthreads();
  int m = tid & 63, cg = tid >> 6;
  float sval[16];
  if (NSPLIT > 1) {
    #pragma unroll
    for (int ci = 0; ci < 16; ++ci) sval[ci] = 0.f;
    const ushort* pb = pacc + (size_t)(b * 64 + mt) * NSPLIT * 4096;
    #pragma unroll
    for (int s = 0; s < NSPLIT; ++s) {
      float wv = wls[s * 64 + m];
      #pragma unroll
      for (int ci = 0; ci < 16; ++ci)
        sval[ci] = fmaf(wv, bf2f(pb[s * 4096 + (cg * 16 + ci) * 64 + m]), sval[ci]);
    }
  } else {
    #pragma unroll
    for (int ci = 0; ci < 16; ++ci)
      sval[ci] = sa[(size_t)(b * 64 + cg * 16 + ci) * 4096 + n0 + m];
  }
  float xcol[64];
  #pragma unroll
  for (int d = 0; d < 64; ++d) xcol[d] = x1f[d * 72 + m];
  union { ushort u[16]; short8v v[2]; } pk;
  #pragma unroll
  for (int ci = 0; ci < 16; ++ci) {
    int c = cg * 16 + ci;
    float o = xcol[c] + sval[ci];
    const float* ar = &acf[c * 72];
    #pragma unroll
    for (int d4 = 0; d4 < 16; ++d4) {
      float4 a4 = *reinterpret_cast<const float4*>(ar + d4 * 4);
      o = fmaf(a4.x, xcol[d4 * 4 + 0], o);
      o = fmaf(a4.y, xcol[d4 * 4 + 1], o);
      o = fmaf(a4.z, xcol[d4 * 4 + 2], o);
      o = fmaf(a4.w, xcol[d4 * 4 + 3], o);
    }
    pk.u[ci] = f2bf(o);
  }
  ushort* dst = yt + (size_t)(b * 4096 + n0 + m) * 64 + cg * 16;
  *reinterpret_cast<short8v*>(dst) = pk.v[0];
  *reinterpret_cast<short8v*>(dst + 8) = pk.v[1];
}

extern "C" void kernel_launch(void* const* d_in, const int* in_sizes, int n_in,
                              void* d_out, int out_size, void* d_ws, size_t ws_size,
                              hipStream_t stream) {
  const float* x       = (const float*)d_in[0];
  const float* w_i     = (const float*)d_in[1];
  const float* b_i     = (const float*)d_in[2];
  const float* gamma_i = (const float*)d_in[3];
  const float* beta_i  = (const float*)d_in[4];
  const float* w_q     = (const float*)d_in[5];
  const float* b_q     = (const float*)d_in[6];
  const float* w_k     = (const float*)d_in[7];
  const float* b_k     = (const float*)d_in[8];
  const float* w_v     = (const float*)d_in[9];
  const float* b_v     = (const float*)d_in[10];
  const float* w_o     = (const float*)d_in[11];
  const float* b_o     = (const float*)d_in[12];
  const float* gamma_o = (const float*)d_in[13];
  const float* beta_o  = (const float*)d_in[14];
  float* ws = (float*)d_ws;
  float* x1 = ws + OFF_X1;
  ushort* qt  = (ushort*)(ws + OFF_QT);
  ushort* kt  = (ushort*)(ws + OFF_KT);
  ushort* vbp = (ushort*)(ws + OFF_VB);
  float* yb = ws + OFF_SA;             // fallback sa
  ushort* ytp = (ushort*)(ws + OFF_YT);
  ushort* xbp = (ushort*)(ws + OFF_XB);
  float* acr = ws + OFF_AC;            // gram accumulator (zeroed by cvt)
  ushort* wbi = (ushort*)(ws + OFF_WBI);
  ushort* wbo = (ushort*)(ws + OFF_WBO);
  float* pt0 = ws + OFF_PT;
  float* pt1 = pt0 + 32;
  unsigned* cnt0 = (unsigned*)(pt0 + 64);
  unsigned* cnt1 = (unsigned*)(pt0 + 65);
  ushort* pacc = (ushort*)(ws + OFF_PO);
  float* pms  = ws + OFF_MS;
  float* outp = (float*)d_out;
  bool split = ws_size >= WS_NEED;

  cvt_k<<<1184, 256, 0, stream>>>(x, xbp, pt0, w_i, w_o, wbi, wbo, acr);

  conv_mfma_k<<<256, 256, 0, stream>>>(xbp, wbi, b_i, gamma_i, beta_i, pt0, cnt0, x1);

  projgram_k<<<384, 256, 0, stream>>>(x1, w_q, b_q, w_k, b_k, w_v, b_v, qt, kt, vbp, acr);

  if (split)
    flash_mfma_k<true><<<1024, 256, 0, stream>>>(qt, kt, vbp, yb, pacc, pms);
  else
    flash_mfma_k<false><<<256, 256, 0, stream>>>(qt, kt, vbp, yb, pacc, pms);

  if (split)
    ca_apply_k<4><<<256, 256, 0, stream>>>(x1, acr, yb, pacc, pms, ytp);
  else
    ca_apply_k<1><<<256, 256, 0, stream>>>(x1, acr, yb, pacc, pms, ytp);

  conv_mfma_k<<<256, 256, 0, stream>>>(ytp, wbo, b_o, gamma_o, beta_o, pt1, cnt1, outp);
}

// Round 11
// 116.324 us; speedup vs baseline: 1.2356x; 1.2356x over previous
//
#include <hip/hip_runtime.h>

// workspace layout (float offsets)
#define OFF_X1  0            // raw conv out fp32 [b][c][n] (t0), 1M floats
#define OFF_SA  1048576      // fallback sa fp32, 1M floats
#define OFF_QT  2097152      // q bf16 [b][n][32] (1 MB)
#define OFF_KT  2359296      // k bf16 [b][n][32]
#define OFF_VB  2621440      // v bf16 [b][c][n] (2 MB)
#define OFF_YT  3145728      // y bf16 [b][n][ci] (2 MB)
#define OFF_XB  3670016      // x bf16 [b][n][ci] (2 MB)
#define OFF_AC  4194304      // gram accumulator fp32 [b][c][d] (64 KB, zeroed by cvt)
#define OFF_WBI 4210688
#define OFF_WBO 4265984
#define OFF_PT  4321280      // GN sums: pt0[32], pt1[32]; pt[96..103] = 16B zero pad for staging
#define OFF_PO  4325376      // split-flash acc partials bf16: 1024 x 4096 (8 MB)
#define OFF_MS  6422528      // split-flash (M,S): 1024 x 128 f32
#define WS_NEED ((size_t)6553600 * 4)

typedef __attribute__((ext_vector_type(8))) short short8v;
typedef __attribute__((ext_vector_type(4))) short short4v;
typedef __attribute__((ext_vector_type(4))) float f32x4;

__device__ __forceinline__ ushort f2bf(float f) {
  union { float f; unsigned u; } v; v.f = f;
  unsigned r = (v.u + 0x7fffu + ((v.u >> 16) & 1u)) >> 16;
  return (ushort)r;
}
__device__ __forceinline__ float bf2f(ushort u) {
  union { unsigned u; float f; } v; v.u = ((unsigned)u) << 16;
  return v.f;
}
__device__ __forceinline__ float max3f(float a, float b, float c) {
  return fmaxf(fmaxf(a, b), c);
}

// async 16B global->LDS (CK idiom: linear LDS dest = wave base + lane*16)
__device__ __forceinline__ void gld_lds16(const ushort* g, ushort* l) {
  __builtin_amdgcn_global_load_lds(
      (const __attribute__((address_space(1))) unsigned*)(unsigned long long)g,
      (__attribute__((address_space(3))) unsigned*)(unsigned long long)l,
      16, 0, 0);
}

// ---- merged converts: x transpose (0..255), weights (256..1119), zero ac+pt (1120..1183) ----
__global__ __launch_bounds__(256) void cvt_k(const float* __restrict__ x, ushort* __restrict__ xb,
    float* __restrict__ pt, const float* __restrict__ wi, const float* __restrict__ wo,
    ushort* __restrict__ wbi, ushort* __restrict__ wbo, float* __restrict__ acr) {
  __shared__ ushort tl[64 * 72];
  int blk = blockIdx.x;
  int t = threadIdx.x;
  if (blk < 256) {
    int b = blk >> 6;
    int n0 = (blk & 63) * 64;
    int ci = t >> 2, q = t & 3;
    const float* src = x + (size_t)(b * 64 + ci) * 4096 + n0 + q * 16;
    #pragma unroll
    for (int i = 0; i < 4; ++i) {
      float4 v = *reinterpret_cast<const float4*>(src + i * 4);
      tl[(q * 16 + i * 4 + 0) * 72 + ci] = f2bf(v.x);
      tl[(q * 16 + i * 4 + 1) * 72 + ci] = f2bf(v.y);
      tl[(q * 16 + i * 4 + 2) * 72 + ci] = f2bf(v.z);
      tl[(q * 16 + i * 4 + 3) * 72 + ci] = f2bf(v.w);
    }
    __syncthreads();
    int n = t >> 2, qq = t & 3;
    ushort* dst = xb + (size_t)(b * 4096 + n0 + n) * 64 + qq * 16;
    *reinterpret_cast<short8v*>(dst) = *reinterpret_cast<const short8v*>(&tl[n * 72 + qq * 16]);
    *reinterpret_cast<short8v*>(dst + 8) = *reinterpret_cast<const short8v*>(&tl[n * 72 + qq * 16 + 8]);
  } else if (blk < 1120) {
    int idx = (blk - 256) * 256 + t;       // 0 .. 221183
    const float* w = idx < 110592 ? wi : wo;
    ushort* wb = idx < 110592 ? wbi : wbo;
    int j = idx < 110592 ? idx : idx - 110592;
    int ci = j & 63, tap = (j >> 6) % 27, co = j / (64 * 27);
    wb[j] = f2bf(w[(co * 64 + ci) * 27 + tap]);
  } else {
    int idx = (blk - 1120) * 256 + t;      // 0 .. 16383
    acr[idx] = 0.f;
    if (blk == 1120 && t < 128) pt[t] = 0.f;   // stats [0..63] + zero pad [96..103]
  }
}

// ------- conv3d implicit GEMM + GN-stats atomics; staging via async global_load_lds -------
__global__ __launch_bounds__(256) void conv_mfma_k(const ushort* __restrict__ xt,
    const ushort* __restrict__ wb, const float* __restrict__ bias, float* __restrict__ out,
    float* __restrict__ ptg, const ushort* __restrict__ zbuf) {
  // chunk-linear tile: 2592 chunks of 16B (+32 pad chunks) = [row(18)*18+w_s][c2]*8 ushorts
  __shared__ __align__(16) ushort xls[2624 * 8];
  __shared__ float sh_st[16];
  int blk = blockIdx.x;
  int h0 = (blk & 3) * 4;
  int d0 = (blk >> 2) & 15;
  int b  = blk >> 6;
  int tid = threadIdx.x;

  const ushort* xtb = xt + (size_t)b * 4096 * 64;
  {
    int wv0 = tid >> 6, ln = tid & 63;
    #pragma unroll
    for (int it = 0; it < 11; ++it) {
      int clbase = (it * 4 + wv0) * 64;
      if (it == 10) {
        if (wv0 != 0) break;
        clbase = 2560;
      }
      int cl = clbase + ln;
      int c2 = cl & 7;
      int rw = cl >> 3;
      int w_s = rw % 18;
      int rowi = rw / 18;
      int dz = rowi / 6, h_s = rowi - dz * 6;
      int d = d0 + dz - 1, h = h0 + h_s - 1, w = w_s - 1;
      int csrc = c2 ^ (w_s & 7);
      const ushort* g = (d >= 0 && d < 16 && h >= 0 && h < 16 && w >= 0 && w < 16)
          ? xtb + (size_t)(d * 256 + h * 16 + w) * 64 + (csrc << 3)
          : zbuf;
      gld_lds16(g, xls + clbase * 8);
    }
  }
  __syncthreads();   // drains vmcnt for the LDS-direct loads

  int wv = tid >> 6, l = tid & 63;
  int wn = wv >> 1, wc = wv & 1;
  int lm = l & 15, lg = l >> 4;

  f32x4 acc[2][2] = {};
  const ushort* wbase0 = wb + (size_t)((wc * 2 + 0) * 16 + lm) * 1728 + lg * 8;
  const ushort* wbase1 = wb + (size_t)((wc * 2 + 1) * 16 + lm) * 1728 + lg * 8;

  #pragma unroll 6
  for (int s = 0; s < 54; ++s) {
    int tap = s >> 1, c0h = s & 1;
    int dz = tap / 9, dyx = tap - dz * 9;
    int dy = dyx / 3, dx = dyx - dy * 3;
    int wrow = lm + dx;
    int chunk = ((c0h * 4 + lg) ^ (wrow & 7)) << 3;
    int r0 = ((dz * 6 + wn * 2 + dy) * 18 + wrow) * 64 + chunk;
    short8v a0 = *reinterpret_cast<const short8v*>(&xls[r0]);
    short8v a1 = *reinterpret_cast<const short8v*>(&xls[r0 + 18 * 64]);
    short8v b0 = *reinterpret_cast<const short8v*>(wbase0 + s * 32);
    short8v b1 = *reinterpret_cast<const short8v*>(wbase1 + s * 32);
    acc[0][0] = __builtin_amdgcn_mfma_f32_16x16x32_bf16(a0, b0, acc[0][0], 0, 0, 0);
    acc[0][1] = __builtin_amdgcn_mfma_f32_16x16x32_bf16(a0, b1, acc[0][1], 0, 0, 0);
    acc[1][0] = __builtin_amdgcn_mfma_f32_16x16x32_bf16(a1, b0, acc[1][0], 0, 0, 0);
    acc[1][1] = __builtin_amdgcn_mfma_f32_16x16x32_bf16(a1, b1, acc[1][1], 0, 0, 0);
  }

  float gs[2], gss[2];
  #pragma unroll
  for (int j = 0; j < 2; ++j) {
    gs[j] = 0.f; gss[j] = 0.f;
    int co = (wc * 2 + j) * 16 + lm;
    float bs = bias[co];
    #pragma unroll
    for (int i = 0; i < 2; ++i) {
      int hh = h0 + wn * 2 + i;
      float4 o;
      o.x = acc[i][j][0] + bs; o.y = acc[i][j][1] + bs;
      o.z = acc[i][j][2] + bs; o.w = acc[i][j][3] + bs;
      gs[j]  += o.x + o.y + o.z + o.w;
      gss[j] = fmaf(o.x, o.x, gss[j]); gss[j] = fmaf(o.y, o.y, gss[j]);
      gss[j] = fmaf(o.z, o.z, gss[j]); gss[j] = fmaf(o.w, o.w, gss[j]);
      *reinterpret_cast<float4*>(&out[(size_t)(b * 64 + co) * 4096 + d0 * 256 + hh * 16 + lg * 4]) = o;
    }
  }
  #pragma unroll
  for (int j = 0; j < 2; ++j) {
    #pragma unroll
    for (int off = 32; off > 0; off >>= 1) {
      gs[j]  += __shfl_xor(gs[j], off);
      gss[j] += __shfl_xor(gss[j], off);
    }
    if (l == 0) { sh_st[wv * 4 + j * 2] = gs[j]; sh_st[wv * 4 + j * 2 + 1] = gss[j]; }
  }
  __syncthreads();
  if (tid < 8) {
    int g = tid >> 1, w2 = tid & 1;
    int wcg = g >> 1, j = g & 1;
    float v = sh_st[wcg * 4 + j * 2 + w2] + sh_st[(wcg + 2) * 4 + j * 2 + w2];
    atomicAdd(&ptg[(b * 4 + g) * 2 + w2], v);
  }
}

// ---------------- groupnorm apply + relu (final output), float4 ----------------
__global__ __launch_bounds__(256) void gn_apply_k(const float* __restrict__ t, const float* __restrict__ pt,
    const float* __restrict__ gamma, const float* __restrict__ beta, float* __restrict__ out) {
  int idx4 = blockIdx.x * 256 + threadIdx.x;     // 1024 blocks: 4 floats/thread
  int c = (idx4 >> 10) & 63, b = idx4 >> 16;
  int bg = b * 4 + (c >> 4);
  float s0 = pt[bg * 2], ss0 = pt[bg * 2 + 1];
  float m = s0 * (1.f / 65536.f);
  float r = rsqrtf(ss0 * (1.f / 65536.f) - m * m + 1e-5f);
  float ga = r * gamma[c], bb2 = beta[c] - m * r * gamma[c];
  float4 v = *reinterpret_cast<const float4*>(t + (size_t)idx4 * 4);
  float4 o;
  o.x = fmaxf(fmaf(v.x, ga, bb2), 0.f);
  o.y = fmaxf(fmaf(v.y, ga, bb2), 0.f);
  o.z = fmaxf(fmaf(v.z, ga, bb2), 0.f);
  o.w = fmaxf(fmaf(v.w, ga, bb2), 0.f);
  *reinterpret_cast<float4*>(out + (size_t)idx4 * 4) = o;
}

// ---------------- merged proj (blocks 0..255) + gram partial w/ atomics (256..383) ----------------
__global__ __launch_bounds__(256) void projgram_k(const float* __restrict__ t0, const float* __restrict__ pt0,
    const float* __restrict__ gamma, const float* __restrict__ beta,
    const float* __restrict__ wq, const float* __restrict__ bq,
    const float* __restrict__ wk, const float* __restrict__ bk,
    const float* __restrict__ wv_, const float* __restrict__ bv,
    ushort* __restrict__ qt, ushort* __restrict__ kt, ushort* __restrict__ vt,
    float* __restrict__ acr) {
  __shared__ __align__(16) float smem[64 * 68];
  int blk = blockIdx.x;
  int tid = threadIdx.x;
  if (blk < 256) {
    // ---- projection (GN inline) ----
    float* xls = smem;
    int b = blk >> 6, n0 = (blk & 63) * 64;
    {
      int ci = tid >> 2, q = tid & 3;
      int bg = b * 4 + (ci >> 4);
      float s0 = pt0[bg * 2], ss0 = pt0[bg * 2 + 1];
      float m = s0 * (1.f / 65536.f);
      float rv = rsqrtf(ss0 * (1.f / 65536.f) - m * m + 1e-5f);
      float ga = rv * gamma[ci], bb2 = beta[ci] - m * rv * gamma[ci];
      const float* src = t0 + (size_t)(b * 64 + ci) * 4096 + n0 + q * 16;
      #pragma unroll
      for (int i = 0; i < 4; ++i) {
        float4 v = *reinterpret_cast<const float4*>(src + i * 4);
        float* d = &xls[ci * 68 + q * 16 + i * 4];
        d[0] = fmaxf(fmaf(v.x, ga, bb2), 0.f);
        d[1] = fmaxf(fmaf(v.y, ga, bb2), 0.f);
        d[2] = fmaxf(fmaf(v.z, ga, bb2), 0.f);
        d[3] = fmaxf(fmaf(v.w, ga, bb2), 0.f);
      }
    }
    __syncthreads();
    int n = tid & 63, og = tid >> 6;
    float xr[64];
    #pragma unroll
    for (int c = 0; c < 64; ++c) xr[c] = xls[c * 68 + n];
    if (og < 2) {
      const float* w  = og == 0 ? wq : wk;
      const float* bb = og == 0 ? bq : bk;
      float scale = og == 0 ? 1.4426950408889634f : 1.0f;
      ushort* outp = og == 0 ? qt : kt;
      union { ushort u[16]; short8v v[2]; } pk;
      #pragma unroll
      for (int o = 0; o < 16; ++o) {
        const float* wr = w + o * 64;
        float acc = bb[o];
        #pragma unroll
        for (int c = 0; c < 64; ++c) acc = fmaf(wr[c], xr[c], acc);
        pk.u[o] = f2bf(acc * scale);
      }
      ushort* dst = outp + (size_t)(b * 4096 + n0 + n) * 32;
      *reinterpret_cast<short8v*>(dst) = pk.v[0];
      *reinterpret_cast<short8v*>(dst + 8) = pk.v[1];
      short8v z = {};
      *reinterpret_cast<short8v*>(dst + 16) = z;
      *reinterpret_cast<short8v*>(dst + 24) = z;
    } else {
      int o0 = (og - 2) * 32;
      #pragma unroll
      for (int o = 0; o < 32; ++o) {
        const float* wr = wv_ + (o0 + o) * 64;
        float acc = bv[o0 + o];
        #pragma unroll
        for (int c = 0; c < 64; ++c) acc = fmaf(wr[c], xr[c], acc);
        vt[(size_t)(b * 64 + o0 + o) * 4096 + n0 + n] = f2bf(acc);
      }
    }
  } else {
    // ---- gram partial (hi/lo bf16 MFMA, GN inline) -> atomicAdd into acr ----
    ushort* hi = (ushort*)smem;
    ushort* lo = hi + 4096;
    int gblk = blk - 256;
    int b = gblk >> 5, ks = gblk & 31;
    int wv = tid >> 6, l = tid & 63, lm = l & 15, lg = l >> 4;
    int wr = wv >> 1, wd = wv & 1;
    f32x4 acc[2][2] = {};
    int sr = tid >> 2, sq = tid & 3;
    int bg = b * 4 + (sr >> 4);
    float s0p = pt0[bg * 2], ss0p = pt0[bg * 2 + 1];
    float mq = s0p * (1.f / 65536.f);
    float rq = rsqrtf(ss0p * (1.f / 65536.f) - mq * mq + 1e-5f);
    float ga = rq * gamma[sr], bb2 = beta[sr] - mq * rq * gamma[sr];
    const float* xb = t0 + (size_t)b * 262144;

    for (int kt2 = 0; kt2 < 2; ++kt2) {
      int n0 = ks * 128 + kt2 * 64;
      __syncthreads();
      const float* src = xb + (size_t)sr * 4096 + n0 + sq * 16;
      #pragma unroll
      for (int c2 = 0; c2 < 2; ++c2) {
        int chunk = sq * 2 + c2;
        int dchunk = chunk ^ (sr & 7);
        short8v hvv, lvv;
        #pragma unroll
        for (int j = 0; j < 8; ++j) {
          float v = fmaxf(fmaf(src[c2 * 8 + j], ga, bb2), 0.f);
          ushort hb = f2bf(v);
          union { float f; unsigned u; } uu; uu.u = ((unsigned)hb) << 16;
          hvv[j] = (short)hb;
          lvv[j] = (short)f2bf(v - uu.f);
        }
        *reinterpret_cast<short8v*>(hi + sr * 64 + dchunk * 8) = hvv;
        *reinterpret_cast<short8v*>(lo + sr * 64 + dchunk * 8) = lvv;
      }
      __syncthreads();
      #pragma unroll
      for (int kk = 0; kk < 2; ++kk) {
        short8v ah[2], al[2], bh[2], bl[2];
        #pragma unroll
        for (int i = 0; i < 2; ++i) {
          int rc = wr * 32 + i * 16 + lm;
          int ca = ((kk * 4 + lg) ^ (rc & 7)) * 8;
          ah[i] = *reinterpret_cast<const short8v*>(hi + rc * 64 + ca);
          al[i] = *reinterpret_cast<const short8v*>(lo + rc * 64 + ca);
          int rd = wd * 32 + i * 16 + lm;
          int cb = ((kk * 4 + lg) ^ (rd & 7)) * 8;
          bh[i] = *reinterpret_cast<const short8v*>(hi + rd * 64 + cb);
          bl[i] = *reinterpret_cast<const short8v*>(lo + rd * 64 + cb);
        }
        #pragma unroll
        for (int i = 0; i < 2; ++i)
          #pragma unroll
          for (int j = 0; j < 2; ++j) {
            acc[i][j] = __builtin_amdgcn_mfma_f32_16x16x32_bf16(ah[i], bh[j], acc[i][j], 0, 0, 0);
            acc[i][j] = __builtin_amdgcn_mfma_f32_16x16x32_bf16(ah[i], bl[j], acc[i][j], 0, 0, 0);
            acc[i][j] = __builtin_amdgcn_mfma_f32_16x16x32_bf16(al[i], bh[j], acc[i][j], 0, 0, 0);
          }
      }
    }
    float* acb = acr + (size_t)b * 4096;
    #pragma unroll
    for (int i = 0; i < 2; ++i)
      #pragma unroll
      for (int j = 0; j < 2; ++j)
        #pragma unroll
        for (int r = 0; r < 4; ++r) {
          int c = wr * 32 + i * 16 + lg * 4 + r;
          int d = wd * 32 + j * 16 + lm;
          atomicAdd(&acb[c * 64 + d], acc[i][j][r]);
        }
  }
}

// ---------------- flash spatial attention, bf16 MFMA, double-buffered, optional split-K ----------------
#define KP 40
#define VP 72
template<bool SPLIT>
__global__ __launch_bounds__(256) void flash_mfma_k(const ushort* __restrict__ qt,
    const ushort* __restrict__ kt, const ushort* __restrict__ vb, float* __restrict__ sa,
    ushort* __restrict__ pacc, float* __restrict__ pms) {
  __shared__ __align__(16) ushort kls[2][64 * KP];
  __shared__ __align__(16) ushort vls[2][64 * VP];
  __shared__ __align__(16) ushort pls[64 * VP];
  int s, mt, b;
  if (SPLIT) { s = blockIdx.x & 3; mt = (blockIdx.x >> 2) & 63; b = blockIdx.x >> 8; }
  else       { s = 0; mt = blockIdx.x & 63; b = blockIdx.x >> 6; }
  const int NT = SPLIT ? 16 : 64;
  int m0 = mt * 64;
  int kofs = s * 1024;
  int tid = threadIdx.x;
  int w = tid >> 6, l = tid & 63;
  int lm = l & 15, lg = l >> 4;

  short8v qf = *reinterpret_cast<const short8v*>(
      qt + (size_t)(b * 4096 + m0 + w * 16 + lm) * 32 + lg * 8);

  f32x4 acc[4] = {};
  float M = -1e30f, S = 0.f;

  int sr = tid >> 2, sq = tid & 3;
  const ushort* ksrc = kt + (size_t)b * 4096 * 32 + (size_t)kofs * 32 + (size_t)sr * 32 + sq * 8;
  const ushort* vsrc = vb + (size_t)b * 64 * 4096 + (size_t)sr * 4096 + kofs + sq * 16;
  int koff = sr * KP + sq * 8;
  int voff = sr * VP + sq * 16;

  {
    short8v kr = *reinterpret_cast<const short8v*>(ksrc);
    short8v v0 = *reinterpret_cast<const short8v*>(vsrc);
    short8v v1 = *reinterpret_cast<const short8v*>(vsrc + 8);
    *reinterpret_cast<short8v*>(&kls[0][koff]) = kr;
    *reinterpret_cast<short8v*>(&vls[0][voff]) = v0;
    *reinterpret_cast<short8v*>(&vls[0][voff + 8]) = v1;
  }

  ushort* plb = &pls[(w * 16 + lm) * VP];

  #pragma unroll 2
  for (int it = 0; it < NT; ++it) {
    int cur = it & 1;
    int nx = it < NT - 1 ? it + 1 : NT - 1;
    short8v knr = *reinterpret_cast<const short8v*>(ksrc + (size_t)nx * 2048);
    short8v vn0 = *reinterpret_cast<const short8v*>(vsrc + nx * 64);
    short8v vn1 = *reinterpret_cast<const short8v*>(vsrc + nx * 64 + 8);

    __syncthreads();

    const ushort* kb  = &kls[cur][0];
    const ushort* vbk = &vls[cur][0];

    f32x4 sf[4];
    #pragma unroll
    for (int nt = 0; nt < 4; ++nt) {
      short8v kf = *reinterpret_cast<const short8v*>(&kb[(nt * 16 + lm) * KP + lg * 8]);
      f32x4 z = {};
      sf[nt] = __builtin_amdgcn_mfma_f32_16x16x32_bf16(kf, qf, z, 0, 0, 0);
    }

    float t0_ = max3f(sf[0][0], sf[0][1], sf[0][2]);
    float t1_ = max3f(sf[0][3], sf[1][0], sf[1][1]);
    float t2_ = max3f(sf[1][2], sf[1][3], sf[2][0]);
    float t3_ = max3f(sf[2][1], sf[2][2], sf[2][3]);
    float t4_ = max3f(sf[3][0], sf[3][1], sf[3][2]);
    float tmax = fmaxf(max3f(t0_, t1_, t2_), max3f(t3_, t4_, sf[3][3]));
    tmax = fmaxf(tmax, __shfl_xor(tmax, 16));
    tmax = fmaxf(tmax, __shfl_xor(tmax, 32));
    if (!__all(tmax <= M)) {
      float Mn = fmaxf(M, tmax);
      float sc = __builtin_amdgcn_exp2f(M - Mn);
      M = Mn;
      S *= sc;
      #pragma unroll
      for (int ct = 0; ct < 4; ++ct)
        #pragma unroll
        for (int r = 0; r < 4; ++r) acc[ct][r] *= sc;
    }
    float tsum = 0.f;
    float p[16];
    #pragma unroll
    for (int nt = 0; nt < 4; ++nt)
      #pragma unroll
      for (int r = 0; r < 4; ++r) {
        float e = __builtin_amdgcn_exp2f(sf[nt][r] - M);
        p[nt * 4 + r] = e;
        tsum += e;
      }
    tsum += __shfl_xor(tsum, 16);
    tsum += __shfl_xor(tsum, 32);
    S += tsum;

    #pragma unroll
    for (int nt = 0; nt < 4; ++nt) {
      unsigned p01, p23;
      asm("v_cvt_pk_bf16_f32 %0, %1, %2" : "=v"(p01) : "v"(p[nt * 4 + 0]), "v"(p[nt * 4 + 1]));
      asm("v_cvt_pk_bf16_f32 %0, %1, %2" : "=v"(p23) : "v"(p[nt * 4 + 2]), "v"(p[nt * 4 + 3]));
      union { unsigned u[2]; short4v v; } pk;
      pk.u[0] = p01; pk.u[1] = p23;
      *reinterpret_cast<short4v*>(plb + nt * 16 + lg * 4) = pk.v;
    }
    asm volatile("s_waitcnt lgkmcnt(0)" ::: "memory");
    __builtin_amdgcn_sched_barrier(0);

    #pragma unroll
    for (int nh = 0; nh < 2; ++nh) {
      short8v pf = *reinterpret_cast<const short8v*>(plb + nh * 32 + lg * 8);
      #pragma unroll
      for (int ct = 0; ct < 4; ++ct) {
        short8v vf = *reinterpret_cast<const short8v*>(&vbk[(ct * 16 + lm) * VP + nh * 32 + lg * 8]);
        acc[ct] = __builtin_amdgcn_mfma_f32_16x16x32_bf16(vf, pf, acc[ct], 0, 0, 0);
      }
    }

    if (it < NT - 1) {
      *reinterpret_cast<short8v*>(&kls[cur ^ 1][koff]) = knr;
      *reinterpret_cast<short8v*>(&vls[cur ^ 1][voff]) = vn0;
      *reinterpret_cast<short8v*>(&vls[cur ^ 1][voff + 8]) = vn1;
    }
  }

  if (SPLIT) {
    int blk2 = (b * 64 + mt) * 4 + s;
    ushort* pa = pacc + (size_t)blk2 * 4096;
    #pragma unroll
    for (int ct = 0; ct < 4; ++ct)
      #pragma unroll
      for (int r = 0; r < 4; ++r)
        pa[(ct * 16 + lg * 4 + r) * 64 + w * 16 + lm] = f2bf(acc[ct][r]);
    if (l < 16) {
      pms[(size_t)blk2 * 128 + (w * 16 + lm) * 2]     = M;
      pms[(size_t)blk2 * 128 + (w * 16 + lm) * 2 + 1] = S;
    }
  } else {
    float inv = 1.f / S;
    #pragma unroll
    for (int ct = 0; ct < 4; ++ct)
      #pragma unroll
      for (int r = 0; r < 4; ++r)
        sa[(size_t)(b * 64 + ct * 16 + lg * 4 + r) * 4096 + m0 + w * 16 + lm] = acc[ct][r] * inv;
  }
}

// ------- y = x1 + sa(+combine) + softmax(gram) @ x1 -> bf16 [b][n][ci]; GN + softmax inline -------
template<int NSPLIT>
__global__ __launch_bounds__(256) void ca_apply_k(const float* __restrict__ t0,
    const float* __restrict__ pt0, const float* __restrict__ gamma, const float* __restrict__ beta,
    const float* __restrict__ acr, const float* __restrict__ sa,
    const ushort* __restrict__ pacc, const float* __restrict__ pms, ushort* __restrict__ yt) {
  __shared__ float x1f[64 * 72];
  __shared__ float acf[64 * 72];
  __shared__ float wls[4 * 64];
  int b = blockIdx.x >> 6, mt = blockIdx.x & 63;
  int n0 = mt * 64;
  int tid = threadIdx.x;
  {
    int d = tid >> 2, q = tid & 3;
    int bg = b * 4 + (d >> 4);
    float s0p = pt0[bg * 2], ss0p = pt0[bg * 2 + 1];
    float mq = s0p * (1.f / 65536.f);
    float rq = rsqrtf(ss0p * (1.f / 65536.f) - mq * mq + 1e-5f);
    float ga = rq * gamma[d], bb2 = beta[d] - mq * rq * gamma[d];
    const float* xs = t0 + (size_t)(b * 64 + d) * 4096 + n0 + q * 16;
    const float* as = acr + (size_t)(b * 64 + d) * 64 + q * 16;
    #pragma unroll
    for (int i = 0; i < 4; ++i) {
      float4 v = *reinterpret_cast<const float4*>(xs + i * 4);
      x1f[d * 72 + q * 16 + i * 4 + 0] = fmaxf(fmaf(v.x, ga, bb2), 0.f);
      x1f[d * 72 + q * 16 + i * 4 + 1] = fmaxf(fmaf(v.y, ga, bb2), 0.f);
      x1f[d * 72 + q * 16 + i * 4 + 2] = fmaxf(fmaf(v.z, ga, bb2), 0.f);
      x1f[d * 72 + q * 16 + i * 4 + 3] = fmaxf(fmaf(v.w, ga, bb2), 0.f);
      float4 a = *reinterpret_cast<const float4*>(as + i * 4);
      acf[d * 72 + q * 16 + i * 4 + 0] = a.x;
      acf[d * 72 + q * 16 + i * 4 + 1] = a.y;
      acf[d * 72 + q * 16 + i * 4 + 2] = a.z;
      acf[d * 72 + q * 16 + i * 4 + 3] = a.w;
    }
  }
  if (NSPLIT > 1 && tid < 64) {
    int m = tid;
    size_t msb = (size_t)(b * 64 + mt) * NSPLIT * 128;
    float Ms[NSPLIT], Ss[NSPLIT];
    float Mg = -1e30f;
    #pragma unroll
    for (int s = 0; s < NSPLIT; ++s) {
      Ms[s] = pms[msb + s * 128 + m * 2];
      Ss[s] = pms[msb + s * 128 + m * 2 + 1];
      Mg = fmaxf(Mg, Ms[s]);
    }
    float Stot = 0.f;
    #pragma unroll
    for (int s = 0; s < NSPLIT; ++s) {
      float wv = __builtin_amdgcn_exp2f(Ms[s] - Mg);
      wls[s * 64 + m] = wv;
      Stot += wv * Ss[s];
    }
    float inv = 1.f / Stot;
    #pragma unroll
    for (int s = 0; s < NSPLIT; ++s) wls[s * 64 + m] *= inv;
  }
  __syncthreads();
  // in-place row softmax of acf (rows = c, over d)
  {
    int r = tid >> 2, q4 = tid & 3;
    float* row = &acf[r * 72 + q4 * 16];
    float mx = -1e30f;
    #pragma unroll
    for (int i = 0; i < 16; ++i) mx = fmaxf(mx, row[i]);
    mx = fmaxf(mx, __shfl_xor(mx, 1));
    mx = fmaxf(mx, __shfl_xor(mx, 2));
    float e[16];
    float sum = 0.f;
    #pragma unroll
    for (int i = 0; i < 16; ++i) { e[i] = __expf(row[i] - mx); sum += e[i]; }
    sum += __shfl_xor(sum, 1);
    sum += __shfl_xor(sum, 2);
    float inv = 1.f / sum;
    #pragma unroll
    for (int i = 0; i < 16; ++i) row[i] = e[i] * inv;
  }
  __syncthreads();
  int m = tid & 63, cg = tid >> 6;
  float sval[16];
  if (NSPLIT > 1) {
    #pragma unroll
    for (int ci = 0; ci < 16; ++ci) sval[ci] = 0.f;
    const ushort* pb = pacc + (size_t)(b * 64 + mt) * NSPLIT * 4096;
    #pragma unroll
    for (int s = 0; s < NSPLIT; ++s) {
      float wv = wls[s * 64 + m];
      #pragma unroll
      for (int ci = 0; ci < 16; ++ci)
        sval[ci] = fmaf(wv, bf2f(pb[s * 4096 + (cg * 16 + ci) * 64 + m]), sval[ci]);
    }
  } else {
    #pragma unroll
    for (int ci = 0; ci < 16; ++ci)
      sval[ci] = sa[(size_t)(b * 64 + cg * 16 + ci) * 4096 + n0 + m];
  }
  float xcol[64];
  #pragma unroll
  for (int d = 0; d < 64; ++d) xcol[d] = x1f[d * 72 + m];
  union { ushort u[16]; short8v v[2]; } pk;
  #pragma unroll
  for (int ci = 0; ci < 16; ++ci) {
    int c = cg * 16 + ci;
    float o = xcol[c] + sval[ci];
    const float* ar = &acf[c * 72];
    #pragma unroll
    for (int d4 = 0; d4 < 16; ++d4) {
      float4 a4 = *reinterpret_cast<const float4*>(ar + d4 * 4);
      o = fmaf(a4.x, xcol[d4 * 4 + 0], o);
      o = fmaf(a4.y, xcol[d4 * 4 + 1], o);
      o = fmaf(a4.z, xcol[d4 * 4 + 2], o);
      o = fmaf(a4.w, xcol[d4 * 4 + 3], o);
    }
    pk.u[ci] = f2bf(o);
  }
  ushort* dst = yt + (size_t)(b * 4096 + n0 + m) * 64 + cg * 16;
  *reinterpret_cast<short8v*>(dst) = pk.v[0];
  *reinterpret_cast<short8v*>(dst + 8) = pk.v[1];
}

extern "C" void kernel_launch(void* const* d_in, const int* in_sizes, int n_in,
                              void* d_out, int out_size, void* d_ws, size_t ws_size,
                              hipStream_t stream) {
  const float* x       = (const float*)d_in[0];
  const float* w_i     = (const float*)d_in[1];
  const float* b_i     = (const float*)d_in[2];
  const float* gamma_i = (const float*)d_in[3];
  const float* beta_i  = (const float*)d_in[4];
  const float* w_q     = (const float*)d_in[5];
  const float* b_q     = (const float*)d_in[6];
  const float* w_k     = (const float*)d_in[7];
  const float* b_k     = (const float*)d_in[8];
  const float* w_v     = (const float*)d_in[9];
  const float* b_v     = (const float*)d_in[10];
  const float* w_o     = (const float*)d_in[11];
  const float* b_o     = (const float*)d_in[12];
  const float* gamma_o = (const float*)d_in[13];
  const float* beta_o  = (const float*)d_in[14];
  float* ws = (float*)d_ws;
  float* t0 = ws + OFF_X1;
  ushort* qt  = (ushort*)(ws + OFF_QT);
  ushort* kt  = (ushort*)(ws + OFF_KT);
  ushort* vbp = (ushort*)(ws + OFF_VB);
  float* yb = ws + OFF_SA;             // fallback sa
  ushort* ytp = (ushort*)(ws + OFF_YT);
  ushort* xbp = (ushort*)(ws + OFF_XB);
  float* acr = ws + OFF_AC;            // gram accumulator (zeroed by cvt)
  ushort* wbi = (ushort*)(ws + OFF_WBI);
  ushort* wbo = (ushort*)(ws + OFF_WBO);
  float* pt0 = ws + OFF_PT;
  float* pt1 = pt0 + 32;
  const ushort* zbuf = (const ushort*)(pt0 + 96);   // 16B of zeros (cvt zeroes pt[0..127])
  ushort* pacc = (ushort*)(ws + OFF_PO);
  float* pms  = ws + OFF_MS;
  float* outp = (float*)d_out;
  bool split = ws_size >= WS_NEED;

  cvt_k<<<1184, 256, 0, stream>>>(x, xbp, pt0, w_i, w_o, wbi, wbo, acr);

  conv_mfma_k<<<256, 256, 0, stream>>>(xbp, wbi, b_i, t0, pt0, zbuf);

  projgram_k<<<384, 256, 0, stream>>>(t0, pt0, gamma_i, beta_i,
                                      w_q, b_q, w_k, b_k, w_v, b_v, qt, kt, vbp, acr);

  if (split)
    flash_mfma_k<true><<<1024, 256, 0, stream>>>(qt, kt, vbp, yb, pacc, pms);
  else
    flash_mfma_k<false><<<256, 256, 0, stream>>>(qt, kt, vbp, yb, pacc, pms);

  if (split)
    ca_apply_k<4><<<256, 256, 0, stream>>>(t0, pt0, gamma_i, beta_i, acr, yb, pacc, pms, ytp);
  else
    ca_apply_k<1><<<256, 256, 0, stream>>>(t0, pt0, gamma_i, beta_i, acr, yb, pacc, pms, ytp);

  conv_mfma_k<<<256, 256, 0, stream>>>(ytp, wbo, b_o, t0, pt1, zbuf);
  gn_apply_k<<<1024, 256, 0, stream>>>(t0, pt1, gamma_o, beta_o, outp);
}

// Round 12
// 114.829 us; speedup vs baseline: 1.2517x; 1.0130x over previous
//
#include <hip/hip_runtime.h>

// workspace layout (float offsets)
#define OFF_X1  0            // raw conv out fp32 [b][c][n] (t0), 1M floats
#define OFF_SA  1048576      // fallback sa fp32, 1M floats
#define OFF_QT  2097152      // q bf16 [b][n][32] (1 MB)
#define OFF_KT  2359296      // k bf16 [b][n][32]
#define OFF_VB  2621440      // v bf16 [b][c][n] (2 MB)
#define OFF_YT  3145728      // y bf16 [b][n][ci] (2 MB)
#define OFF_XB  3670016      // x bf16 [b][n][ci] (2 MB)
#define OFF_AC  4194304      // gram accumulator fp32 [b][c][d] (64 KB, zeroed by cvt)
#define OFF_WBI 4210688
#define OFF_WBO 4265984
#define OFF_PT  4321280      // GN sums: pt0[32], pt1[32]; pt[96..103] = 16B zero pad for staging
#define OFF_PO  4325376      // split-flash acc partials bf16: 1024 x 4096 (8 MB)
#define OFF_MS  6422528      // split-flash (M,S): 1024 x 128 f32
#define WS_NEED ((size_t)6553600 * 4)

typedef __attribute__((ext_vector_type(8))) short short8v;
typedef __attribute__((ext_vector_type(4))) short short4v;
typedef __attribute__((ext_vector_type(4))) float f32x4;

__device__ __forceinline__ ushort f2bf(float f) {
  union { float f; unsigned u; } v; v.f = f;
  unsigned r = (v.u + 0x7fffu + ((v.u >> 16) & 1u)) >> 16;
  return (ushort)r;
}
__device__ __forceinline__ float bf2f(ushort u) {
  union { unsigned u; float f; } v; v.u = ((unsigned)u) << 16;
  return v.f;
}
__device__ __forceinline__ float max3f(float a, float b, float c) {
  return fmaxf(fmaxf(a, b), c);
}

// async 16B global->LDS (linear LDS dest = wave base + lane*16)
__device__ __forceinline__ void gld_lds16(const ushort* g, ushort* l) {
  __builtin_amdgcn_global_load_lds(
      (const __attribute__((address_space(1))) unsigned*)(unsigned long long)g,
      (__attribute__((address_space(3))) unsigned*)(unsigned long long)l,
      16, 0, 0);
}

// ---- merged converts: x transpose (0..255), weights (256..1119), zero ac+pt (1120..1183) ----
__global__ __launch_bounds__(256) void cvt_k(const float* __restrict__ x, ushort* __restrict__ xb,
    float* __restrict__ pt, const float* __restrict__ wi, const float* __restrict__ wo,
    ushort* __restrict__ wbi, ushort* __restrict__ wbo, float* __restrict__ acr) {
  __shared__ ushort tl[64 * 72];
  int blk = blockIdx.x;
  int t = threadIdx.x;
  if (blk < 256) {
    int b = blk >> 6;
    int n0 = (blk & 63) * 64;
    int ci = t >> 2, q = t & 3;
    const float* src = x + (size_t)(b * 64 + ci) * 4096 + n0 + q * 16;
    #pragma unroll
    for (int i = 0; i < 4; ++i) {
      float4 v = *reinterpret_cast<const float4*>(src + i * 4);
      tl[(q * 16 + i * 4 + 0) * 72 + ci] = f2bf(v.x);
      tl[(q * 16 + i * 4 + 1) * 72 + ci] = f2bf(v.y);
      tl[(q * 16 + i * 4 + 2) * 72 + ci] = f2bf(v.z);
      tl[(q * 16 + i * 4 + 3) * 72 + ci] = f2bf(v.w);
    }
    __syncthreads();
    int n = t >> 2, qq = t & 3;
    ushort* dst = xb + (size_t)(b * 4096 + n0 + n) * 64 + qq * 16;
    *reinterpret_cast<short8v*>(dst) = *reinterpret_cast<const short8v*>(&tl[n * 72 + qq * 16]);
    *reinterpret_cast<short8v*>(dst + 8) = *reinterpret_cast<const short8v*>(&tl[n * 72 + qq * 16 + 8]);
  } else if (blk < 1120) {
    int idx = (blk - 256) * 256 + t;       // 0 .. 221183
    const float* w = idx < 110592 ? wi : wo;
    ushort* wb = idx < 110592 ? wbi : wbo;
    int j = idx < 110592 ? idx : idx - 110592;
    int ci = j & 63, tap = (j >> 6) % 27, co = j / (64 * 27);
    wb[j] = f2bf(w[(co * 64 + ci) * 27 + tap]);
  } else {
    int idx = (blk - 1120) * 256 + t;      // 0 .. 16383
    acr[idx] = 0.f;
    if (blk == 1120 && t < 128) pt[t] = 0.f;   // stats [0..63] + zero pad [96..103]
  }
}

// ------- conv3d implicit GEMM (8 waves: 2 h-pairs x 4 co-groups) + GN-stats atomics -------
__global__ __launch_bounds__(512) void conv_mfma_k(const ushort* __restrict__ xt,
    const ushort* __restrict__ wb, const float* __restrict__ bias, float* __restrict__ out,
    float* __restrict__ ptg, const ushort* __restrict__ zbuf) {
  // chunk-linear tile: 2592 chunks of 16B (+32 pad) = [row(18)*18+w_s][c2]*8 ushorts
  __shared__ __align__(16) ushort xls[2624 * 8];
  __shared__ float sh_st[16];
  int blk = blockIdx.x;
  int h0 = (blk & 3) * 4;
  int d0 = (blk >> 2) & 15;
  int b  = blk >> 6;
  int tid = threadIdx.x;

  const ushort* xtb = xt + (size_t)b * 4096 * 64;
  {
    int wv0 = tid >> 6, ln = tid & 63;
    #pragma unroll
    for (int it = 0; it < 6; ++it) {
      int clbase;
      if (it < 5) clbase = (it * 8 + wv0) * 64;
      else { if (wv0 != 0) break; clbase = 2560; }
      int cl = clbase + ln;
      int c2 = cl & 7;
      int rw = cl >> 3;
      int w_s = rw % 18;
      int rowi = rw / 18;
      int dz = rowi / 6, h_s = rowi - dz * 6;
      int d = d0 + dz - 1, h = h0 + h_s - 1, w = w_s - 1;
      int csrc = c2 ^ (w_s & 7);
      const ushort* g = (d >= 0 && d < 16 && h >= 0 && h < 16 && w >= 0 && w < 16)
          ? xtb + (size_t)(d * 256 + h * 16 + w) * 64 + (csrc << 3)
          : zbuf;
      gld_lds16(g, xls + clbase * 8);
    }
  }
  __syncthreads();   // drains vmcnt for the LDS-direct loads

  int wv = tid >> 6, l = tid & 63;
  int wc4 = wv & 3, wn = wv >> 2;
  int lm = l & 15, lg = l >> 4;

  f32x4 acc[2] = {};
  const ushort* wbase = wb + (size_t)((wc4 * 16 + lm) * 1728) + lg * 8;

  #pragma unroll 6
  for (int s = 0; s < 54; ++s) {
    int tap = s >> 1, c0h = s & 1;
    int dz = tap / 9, dyx = tap - dz * 9;
    int dy = dyx / 3, dx = dyx - dy * 3;
    int wrow = lm + dx;
    int chunk = ((c0h * 4 + lg) ^ (wrow & 7)) << 3;
    int r0 = ((dz * 6 + wn * 2 + dy) * 18 + wrow) * 64 + chunk;
    short8v a0 = *reinterpret_cast<const short8v*>(&xls[r0]);
    short8v a1 = *reinterpret_cast<const short8v*>(&xls[r0 + 18 * 64]);
    short8v b0 = *reinterpret_cast<const short8v*>(wbase + s * 32);
    acc[0] = __builtin_amdgcn_mfma_f32_16x16x32_bf16(a0, b0, acc[0], 0, 0, 0);
    acc[1] = __builtin_amdgcn_mfma_f32_16x16x32_bf16(a1, b0, acc[1], 0, 0, 0);
  }

  float gs = 0.f, gss = 0.f;
  int co = wc4 * 16 + lm;
  float bs = bias[co];
  #pragma unroll
  for (int i = 0; i < 2; ++i) {
    int hh = h0 + wn * 2 + i;
    float4 o;
    o.x = acc[i][0] + bs; o.y = acc[i][1] + bs;
    o.z = acc[i][2] + bs; o.w = acc[i][3] + bs;
    gs  += o.x + o.y + o.z + o.w;
    gss = fmaf(o.x, o.x, gss); gss = fmaf(o.y, o.y, gss);
    gss = fmaf(o.z, o.z, gss); gss = fmaf(o.w, o.w, gss);
    *reinterpret_cast<float4*>(&out[(size_t)(b * 64 + co) * 4096 + d0 * 256 + hh * 16 + lg * 4]) = o;
  }
  #pragma unroll
  for (int off = 32; off > 0; off >>= 1) {
    gs  += __shfl_xor(gs, off);
    gss += __shfl_xor(gss, off);
  }
  if (l == 0) { sh_st[wv * 2] = gs; sh_st[wv * 2 + 1] = gss; }
  __syncthreads();
  if (tid < 8) {
    int g = tid >> 1, w2 = tid & 1;      // g = co-group = GN group
    float v = sh_st[g * 2 + w2] + sh_st[(4 + g) * 2 + w2];   // wn=0 (wv=g) + wn=1 (wv=4+g)
    atomicAdd(&ptg[(b * 4 + g) * 2 + w2], v);
  }
}

// ---------------- groupnorm apply + relu (final output), float4 ----------------
__global__ __launch_bounds__(256) void gn_apply_k(const float* __restrict__ t, const float* __restrict__ pt,
    const float* __restrict__ gamma, const float* __restrict__ beta, float* __restrict__ out) {
  int idx4 = blockIdx.x * 256 + threadIdx.x;     // 1024 blocks: 4 floats/thread
  int c = (idx4 >> 10) & 63, b = idx4 >> 16;
  int bg = b * 4 + (c >> 4);
  float s0 = pt[bg * 2], ss0 = pt[bg * 2 + 1];
  float m = s0 * (1.f / 65536.f);
  float r = rsqrtf(ss0 * (1.f / 65536.f) - m * m + 1e-5f);
  float ga = r * gamma[c], bb2 = beta[c] - m * r * gamma[c];
  float4 v = *reinterpret_cast<const float4*>(t + (size_t)idx4 * 4);
  float4 o;
  o.x = fmaxf(fmaf(v.x, ga, bb2), 0.f);
  o.y = fmaxf(fmaf(v.y, ga, bb2), 0.f);
  o.z = fmaxf(fmaf(v.z, ga, bb2), 0.f);
  o.w = fmaxf(fmaf(v.w, ga, bb2), 0.f);
  *reinterpret_cast<float4*>(out + (size_t)idx4 * 4) = o;
}

// ---------------- merged gram partial (blocks 0..127, dispatched first) + proj (128..383) ----------------
__global__ __launch_bounds__(256) void projgram_k(const float* __restrict__ t0, const float* __restrict__ pt0,
    const float* __restrict__ gamma, const float* __restrict__ beta,
    const float* __restrict__ wq, const float* __restrict__ bq,
    const float* __restrict__ wk, const float* __restrict__ bk,
    const float* __restrict__ wv_, const float* __restrict__ bv,
    ushort* __restrict__ qt, ushort* __restrict__ kt, ushort* __restrict__ vt,
    float* __restrict__ acr) {
  __shared__ __align__(16) float smem[64 * 68];
  int blk = blockIdx.x;
  int tid = threadIdx.x;
  if (blk >= 128) {
    // ---- projection (GN inline) ----
    float* xls = smem;
    int pblk = blk - 128;
    int b = pblk >> 6, n0 = (pblk & 63) * 64;
    {
      int ci = tid >> 2, q = tid & 3;
      int bg = b * 4 + (ci >> 4);
      float s0 = pt0[bg * 2], ss0 = pt0[bg * 2 + 1];
      float m = s0 * (1.f / 65536.f);
      float rv = rsqrtf(ss0 * (1.f / 65536.f) - m * m + 1e-5f);
      float ga = rv * gamma[ci], bb2 = beta[ci] - m * rv * gamma[ci];
      const float* src = t0 + (size_t)(b * 64 + ci) * 4096 + n0 + q * 16;
      #pragma unroll
      for (int i = 0; i < 4; ++i) {
        float4 v = *reinterpret_cast<const float4*>(src + i * 4);
        float* d = &xls[ci * 68 + q * 16 + i * 4];
        d[0] = fmaxf(fmaf(v.x, ga, bb2), 0.f);
        d[1] = fmaxf(fmaf(v.y, ga, bb2), 0.f);
        d[2] = fmaxf(fmaf(v.z, ga, bb2), 0.f);
        d[3] = fmaxf(fmaf(v.w, ga, bb2), 0.f);
      }
    }
    __syncthreads();
    int n = tid & 63, og = tid >> 6;
    float xr[64];
    #pragma unroll
    for (int c = 0; c < 64; ++c) xr[c] = xls[c * 68 + n];
    if (og < 2) {
      const float* w  = og == 0 ? wq : wk;
      const float* bb = og == 0 ? bq : bk;
      float scale = og == 0 ? 1.4426950408889634f : 1.0f;
      ushort* outp = og == 0 ? qt : kt;
      union { ushort u[16]; short8v v[2]; } pk;
      #pragma unroll
      for (int o = 0; o < 16; ++o) {
        const float* wr = w + o * 64;
        float acc = bb[o];
        #pragma unroll
        for (int c = 0; c < 64; ++c) acc = fmaf(wr[c], xr[c], acc);
        pk.u[o] = f2bf(acc * scale);
      }
      ushort* dst = outp + (size_t)(b * 4096 + n0 + n) * 32;
      *reinterpret_cast<short8v*>(dst) = pk.v[0];
      *reinterpret_cast<short8v*>(dst + 8) = pk.v[1];
      short8v z = {};
      *reinterpret_cast<short8v*>(dst + 16) = z;
      *reinterpret_cast<short8v*>(dst + 24) = z;
    } else {
      int o0 = (og - 2) * 32;
      #pragma unroll
      for (int o = 0; o < 32; ++o) {
        const float* wr = wv_ + (o0 + o) * 64;
        float acc = bv[o0 + o];
        #pragma unroll
        for (int c = 0; c < 64; ++c) acc = fmaf(wr[c], xr[c], acc);
        vt[(size_t)(b * 64 + o0 + o) * 4096 + n0 + n] = f2bf(acc);
      }
    }
  } else {
    // ---- gram partial (hi/lo bf16 MFMA, GN inline) -> atomicAdd into acr ----
    ushort* hi = (ushort*)smem;
    ushort* lo = hi + 4096;
    int gblk = blk;
    int b = gblk >> 5, ks = gblk & 31;
    int wv = tid >> 6, l = tid & 63, lm = l & 15, lg = l >> 4;
    int wr = wv >> 1, wd = wv & 1;
    f32x4 acc[2][2] = {};
    int sr = tid >> 2, sq = tid & 3;
    int bg = b * 4 + (sr >> 4);
    float s0p = pt0[bg * 2], ss0p = pt0[bg * 2 + 1];
    float mq = s0p * (1.f / 65536.f);
    float rq = rsqrtf(ss0p * (1.f / 65536.f) - mq * mq + 1e-5f);
    float ga = rq * gamma[sr], bb2 = beta[sr] - mq * rq * gamma[sr];
    const float* xb = t0 + (size_t)b * 262144;

    for (int kt2 = 0; kt2 < 2; ++kt2) {
      int n0 = ks * 128 + kt2 * 64;
      __syncthreads();
      const float* src = xb + (size_t)sr * 4096 + n0 + sq * 16;
      #pragma unroll
      for (int c2 = 0; c2 < 2; ++c2) {
        int chunk = sq * 2 + c2;
        int dchunk = chunk ^ (sr & 7);
        short8v hvv, lvv;
        #pragma unroll
        for (int j = 0; j < 8; ++j) {
          float v = fmaxf(fmaf(src[c2 * 8 + j], ga, bb2), 0.f);
          ushort hb = f2bf(v);
          union { float f; unsigned u; } uu; uu.u = ((unsigned)hb) << 16;
          hvv[j] = (short)hb;
          lvv[j] = (short)f2bf(v - uu.f);
        }
        *reinterpret_cast<short8v*>(hi + sr * 64 + dchunk * 8) = hvv;
        *reinterpret_cast<short8v*>(lo + sr * 64 + dchunk * 8) = lvv;
      }
      __syncthreads();
      #pragma unroll
      for (int kk = 0; kk < 2; ++kk) {
        short8v ah[2], al[2], bh[2], bl[2];
        #pragma unroll
        for (int i = 0; i < 2; ++i) {
          int rc = wr * 32 + i * 16 + lm;
          int ca = ((kk * 4 + lg) ^ (rc & 7)) * 8;
          ah[i] = *reinterpret_cast<const short8v*>(hi + rc * 64 + ca);
          al[i] = *reinterpret_cast<const short8v*>(lo + rc * 64 + ca);
          int rd = wd * 32 + i * 16 + lm;
          int cb = ((kk * 4 + lg) ^ (rd & 7)) * 8;
          bh[i] = *reinterpret_cast<const short8v*>(hi + rd * 64 + cb);
          bl[i] = *reinterpret_cast<const short8v*>(lo + rd * 64 + cb);
        }
        #pragma unroll
        for (int i = 0; i < 2; ++i)
          #pragma unroll
          for (int j = 0; j < 2; ++j) {
            acc[i][j] = __builtin_amdgcn_mfma_f32_16x16x32_bf16(ah[i], bh[j], acc[i][j], 0, 0, 0);
            acc[i][j] = __builtin_amdgcn_mfma_f32_16x16x32_bf16(ah[i], bl[j], acc[i][j], 0, 0, 0);
            acc[i][j] = __builtin_amdgcn_mfma_f32_16x16x32_bf16(al[i], bh[j], acc[i][j], 0, 0, 0);
          }
      }
    }
    float* acb = acr + (size_t)b * 4096;
    #pragma unroll
    for (int i = 0; i < 2; ++i)
      #pragma unroll
      for (int j = 0; j < 2; ++j)
        #pragma unroll
        for (int r = 0; r < 4; ++r) {
          int c = wr * 32 + i * 16 + lg * 4 + r;
          int d = wd * 32 + j * 16 + lm;
          atomicAdd(&acb[c * 64 + d], acc[i][j][r]);
        }
  }
}

// ---------------- flash spatial attention, bf16 MFMA, double-buffered, optional split-K ----------------
#define KP 40
#define VP 72
template<bool SPLIT>
__global__ __launch_bounds__(256) void flash_mfma_k(const ushort* __restrict__ qt,
    const ushort* __restrict__ kt, const ushort* __restrict__ vb, float* __restrict__ sa,
    ushort* __restrict__ pacc, float* __restrict__ pms) {
  __shared__ __align__(16) ushort kls[2][64 * KP];
  __shared__ __align__(16) ushort vls[2][64 * VP];
  __shared__ __align__(16) ushort pls[64 * VP];
  int s, mt, b;
  if (SPLIT) { s = blockIdx.x & 3; mt = (blockIdx.x >> 2) & 63; b = blockIdx.x >> 8; }
  else       { s = 0; mt = blockIdx.x & 63; b = blockIdx.x >> 6; }
  const int NT = SPLIT ? 16 : 64;
  int m0 = mt * 64;
  int kofs = s * 1024;
  int tid = threadIdx.x;
  int w = tid >> 6, l = tid & 63;
  int lm = l & 15, lg = l >> 4;

  short8v qf = *reinterpret_cast<const short8v*>(
      qt + (size_t)(b * 4096 + m0 + w * 16 + lm) * 32 + lg * 8);

  f32x4 acc[4] = {};
  float M = -1e30f, S = 0.f;

  int sr = tid >> 2, sq = tid & 3;
  const ushort* ksrc = kt + (size_t)b * 4096 * 32 + (size_t)kofs * 32 + (size_t)sr * 32 + sq * 8;
  const ushort* vsrc = vb + (size_t)b * 64 * 4096 + (size_t)sr * 4096 + kofs + sq * 16;
  int koff = sr * KP + sq * 8;
  int voff = sr * VP + sq * 16;

  {
    short8v kr = *reinterpret_cast<const short8v*>(ksrc);
    short8v v0 = *reinterpret_cast<const short8v*>(vsrc);
    short8v v1 = *reinterpret_cast<const short8v*>(vsrc + 8);
    *reinterpret_cast<short8v*>(&kls[0][koff]) = kr;
    *reinterpret_cast<short8v*>(&vls[0][voff]) = v0;
    *reinterpret_cast<short8v*>(&vls[0][voff + 8]) = v1;
  }

  ushort* plb = &pls[(w * 16 + lm) * VP];

  #pragma unroll 2
  for (int it = 0; it < NT; ++it) {
    int cur = it & 1;
    int nx = it < NT - 1 ? it + 1 : NT - 1;
    short8v knr = *reinterpret_cast<const short8v*>(ksrc + (size_t)nx * 2048);
    short8v vn0 = *reinterpret_cast<const short8v*>(vsrc + nx * 64);
    short8v vn1 = *reinterpret_cast<const short8v*>(vsrc + nx * 64 + 8);

    __syncthreads();

    const ushort* kb  = &kls[cur][0];
    const ushort* vbk = &vls[cur][0];

    f32x4 sf[4];
    #pragma unroll
    for (int nt = 0; nt < 4; ++nt) {
      short8v kf = *reinterpret_cast<const short8v*>(&kb[(nt * 16 + lm) * KP + lg * 8]);
      f32x4 z = {};
      sf[nt] = __builtin_amdgcn_mfma_f32_16x16x32_bf16(kf, qf, z, 0, 0, 0);
    }

    float t0_ = max3f(sf[0][0], sf[0][1], sf[0][2]);
    float t1_ = max3f(sf[0][3], sf[1][0], sf[1][1]);
    float t2_ = max3f(sf[1][2], sf[1][3], sf[2][0]);
    float t3_ = max3f(sf[2][1], sf[2][2], sf[2][3]);
    float t4_ = max3f(sf[3][0], sf[3][1], sf[3][2]);
    float tmax = fmaxf(max3f(t0_, t1_, t2_), max3f(t3_, t4_, sf[3][3]));
    tmax = fmaxf(tmax, __shfl_xor(tmax, 16));
    tmax = fmaxf(tmax, __shfl_xor(tmax, 32));
    if (!__all(tmax <= M)) {
      float Mn = fmaxf(M, tmax);
      float sc = __builtin_amdgcn_exp2f(M - Mn);
      M = Mn;
      S *= sc;
      #pragma unroll
      for (int ct = 0; ct < 4; ++ct)
        #pragma unroll
        for (int r = 0; r < 4; ++r) acc[ct][r] *= sc;
    }
    float tsum = 0.f;
    float p[16];
    #pragma unroll
    for (int nt = 0; nt < 4; ++nt)
      #pragma unroll
      for (int r = 0; r < 4; ++r) {
        float e = __builtin_amdgcn_exp2f(sf[nt][r] - M);
        p[nt * 4 + r] = e;
        tsum += e;
      }
    tsum += __shfl_xor(tsum, 16);
    tsum += __shfl_xor(tsum, 32);
    S += tsum;

    #pragma unroll
    for (int nt = 0; nt < 4; ++nt) {
      unsigned p01, p23;
      asm("v_cvt_pk_bf16_f32 %0, %1, %2" : "=v"(p01) : "v"(p[nt * 4 + 0]), "v"(p[nt * 4 + 1]));
      asm("v_cvt_pk_bf16_f32 %0, %1, %2" : "=v"(p23) : "v"(p[nt * 4 + 2]), "v"(p[nt * 4 + 3]));
      union { unsigned u[2]; short4v v; } pk;
      pk.u[0] = p01; pk.u[1] = p23;
      *reinterpret_cast<short4v*>(plb + nt * 16 + lg * 4) = pk.v;
    }
    asm volatile("s_waitcnt lgkmcnt(0)" ::: "memory");
    __builtin_amdgcn_sched_barrier(0);

    #pragma unroll
    for (int nh = 0; nh < 2; ++nh) {
      short8v pf = *reinterpret_cast<const short8v*>(plb + nh * 32 + lg * 8);
      #pragma unroll
      for (int ct = 0; ct < 4; ++ct) {
        short8v vf = *reinterpret_cast<const short8v*>(&vbk[(ct * 16 + lm) * VP + nh * 32 + lg * 8]);
        acc[ct] = __builtin_amdgcn_mfma_f32_16x16x32_bf16(vf, pf, acc[ct], 0, 0, 0);
      }
    }

    if (it < NT - 1) {
      *reinterpret_cast<short8v*>(&kls[cur ^ 1][koff]) = knr;
      *reinterpret_cast<short8v*>(&vls[cur ^ 1][voff]) = vn0;
      *reinterpret_cast<short8v*>(&vls[cur ^ 1][voff + 8]) = vn1;
    }
  }

  if (SPLIT) {
    int blk2 = (b * 64 + mt) * 4 + s;
    ushort* pa = pacc + (size_t)blk2 * 4096;
    #pragma unroll
    for (int ct = 0; ct < 4; ++ct)
      #pragma unroll
      for (int r = 0; r < 4; ++r)
        pa[(ct * 16 + lg * 4 + r) * 64 + w * 16 + lm] = f2bf(acc[ct][r]);
    if (l < 16) {
      pms[(size_t)blk2 * 128 + (w * 16 + lm) * 2]     = M;
      pms[(size_t)blk2 * 128 + (w * 16 + lm) * 2 + 1] = S;
    }
  } else {
    float inv = 1.f / S;
    #pragma unroll
    for (int ct = 0; ct < 4; ++ct)
      #pragma unroll
      for (int r = 0; r < 4; ++r)
        sa[(size_t)(b * 64 + ct * 16 + lg * 4 + r) * 4096 + m0 + w * 16 + lm] = acc[ct][r] * inv;
  }
}

// ------- y = x1 + sa(+combine) + softmax(gram) @ x1 -> bf16 [b][n][ci]; 8 waves -------
template<int NSPLIT>
__global__ __launch_bounds__(512) void ca_apply_k(const float* __restrict__ t0,
    const float* __restrict__ pt0, const float* __restrict__ gamma, const float* __restrict__ beta,
    const float* __restrict__ acr, const float* __restrict__ sa,
    const ushort* __restrict__ pacc, const float* __restrict__ pms, ushort* __restrict__ yt) {
  __shared__ float x1f[64 * 72];
  __shared__ float acf[64 * 72];
  __shared__ float wls[4 * 64];
  int b = blockIdx.x >> 6, mt = blockIdx.x & 63;
  int n0 = mt * 64;
  int tid = threadIdx.x;
  {
    int d = tid >> 3, q = tid & 7;     // 8 cols per thread
    int bg = b * 4 + (d >> 4);
    float s0p = pt0[bg * 2], ss0p = pt0[bg * 2 + 1];
    float mq = s0p * (1.f / 65536.f);
    float rq = rsqrtf(ss0p * (1.f / 65536.f) - mq * mq + 1e-5f);
    float ga = rq * gamma[d], bb2 = beta[d] - mq * rq * gamma[d];
    const float* xs = t0 + (size_t)(b * 64 + d) * 4096 + n0 + q * 8;
    const float* as = acr + (size_t)(b * 64 + d) * 64 + q * 8;
    #pragma unroll
    for (int i = 0; i < 2; ++i) {
      float4 v = *reinterpret_cast<const float4*>(xs + i * 4);
      x1f[d * 72 + q * 8 + i * 4 + 0] = fmaxf(fmaf(v.x, ga, bb2), 0.f);
      x1f[d * 72 + q * 8 + i * 4 + 1] = fmaxf(fmaf(v.y, ga, bb2), 0.f);
      x1f[d * 72 + q * 8 + i * 4 + 2] = fmaxf(fmaf(v.z, ga, bb2), 0.f);
      x1f[d * 72 + q * 8 + i * 4 + 3] = fmaxf(fmaf(v.w, ga, bb2), 0.f);
      float4 a = *reinterpret_cast<const float4*>(as + i * 4);
      acf[d * 72 + q * 8 + i * 4 + 0] = a.x;
      acf[d * 72 + q * 8 + i * 4 + 1] = a.y;
      acf[d * 72 + q * 8 + i * 4 + 2] = a.z;
      acf[d * 72 + q * 8 + i * 4 + 3] = a.w;
    }
  }
  if (NSPLIT > 1 && tid < 64) {
    int m = tid;
    size_t msb = (size_t)(b * 64 + mt) * NSPLIT * 128;
    float Ms[NSPLIT], Ss[NSPLIT];
    float Mg = -1e30f;
    #pragma unroll
    for (int s = 0; s < NSPLIT; ++s) {
      Ms[s] = pms[msb + s * 128 + m * 2];
      Ss[s] = pms[msb + s * 128 + m * 2 + 1];
      Mg = fmaxf(Mg, Ms[s]);
    }
    float Stot = 0.f;
    #pragma unroll
    for (int s = 0; s < NSPLIT; ++s) {
      float wv = __builtin_amdgcn_exp2f(Ms[s] - Mg);
      wls[s * 64 + m] = wv;
      Stot += wv * Ss[s];
    }
    float inv = 1.f / Stot;
    #pragma unroll
    for (int s = 0; s < NSPLIT; ++s) wls[s * 64 + m] *= inv;
  }
  __syncthreads();
  // in-place row softmax of acf (rows = c, over d); 8 threads/row
  {
    int r = tid >> 3, q4 = tid & 7;
    float* row = &acf[r * 72 + q4 * 8];
    float mx = -1e30f;
    #pragma unroll
    for (int i = 0; i < 8; ++i) mx = fmaxf(mx, row[i]);
    mx = fmaxf(mx, __shfl_xor(mx, 1));
    mx = fmaxf(mx, __shfl_xor(mx, 2));
    mx = fmaxf(mx, __shfl_xor(mx, 4));
    float e[8];
    float sum = 0.f;
    #pragma unroll
    for (int i = 0; i < 8; ++i) { e[i] = __expf(row[i] - mx); sum += e[i]; }
    sum += __shfl_xor(sum, 1);
    sum += __shfl_xor(sum, 2);
    sum += __shfl_xor(sum, 4);
    float inv = 1.f / sum;
    #pragma unroll
    for (int i = 0; i < 8; ++i) row[i] = e[i] * inv;
  }
  __syncthreads();
  int m = tid & 63, cg = tid >> 6;    // 8 waves: 8 channels each
  float sval[8];
  if (NSPLIT > 1) {
    #pragma unroll
    for (int ci = 0; ci < 8; ++ci) sval[ci] = 0.f;
    const ushort* pb = pacc + (size_t)(b * 64 + mt) * NSPLIT * 4096;
    #pragma unroll
    for (int s = 0; s < NSPLIT; ++s) {
      float wv = wls[s * 64 + m];
      #pragma unroll
      for (int ci = 0; ci < 8; ++ci)
        sval[ci] = fmaf(wv, bf2f(pb[s * 4096 + (cg * 8 + ci) * 64 + m]), sval[ci]);
    }
  } else {
    #pragma unroll
    for (int ci = 0; ci < 8; ++ci)
      sval[ci] = sa[(size_t)(b * 64 + cg * 8 + ci) * 4096 + n0 + m];
  }
  float xcol[64];
  #pragma unroll
  for (int d = 0; d < 64; ++d) xcol[d] = x1f[d * 72 + m];
  union { ushort u[8]; short8v v; } pk;
  #pragma unroll
  for (int ci = 0; ci < 8; ++ci) {
    int c = cg * 8 + ci;
    float o = xcol[c] + sval[ci];
    const float* ar = &acf[c * 72];
    #pragma unroll
    for (int d4 = 0; d4 < 16; ++d4) {
      float4 a4 = *reinterpret_cast<const float4*>(ar + d4 * 4);
      o = fmaf(a4.x, xcol[d4 * 4 + 0], o);
      o = fmaf(a4.y, xcol[d4 * 4 + 1], o);
      o = fmaf(a4.z, xcol[d4 * 4 + 2], o);
      o = fmaf(a4.w, xcol[d4 * 4 + 3], o);
    }
    pk.u[ci] = f2bf(o);
  }
  ushort* dst = yt + (size_t)(b * 4096 + n0 + m) * 64 + cg * 8;
  *reinterpret_cast<short8v*>(dst) = pk.v;
}

extern "C" void kernel_launch(void* const* d_in, const int* in_sizes, int n_in,
                              void* d_out, int out_size, void* d_ws, size_t ws_size,
                              hipStream_t stream) {
  const float* x       = (const float*)d_in[0];
  const float* w_i     = (const float*)d_in[1];
  const float* b_i     = (const float*)d_in[2];
  const float* gamma_i = (const float*)d_in[3];
  const float* beta_i  = (const float*)d_in[4];
  const float* w_q     = (const float*)d_in[5];
  const float* b_q     = (const float*)d_in[6];
  const float* w_k     = (const float*)d_in[7];
  const float* b_k     = (const float*)d_in[8];
  const float* w_v     = (const float*)d_in[9];
  const float* b_v     = (const float*)d_in[10];
  const float* w_o     = (const float*)d_in[11];
  const float* b_o     = (const float*)d_in[12];
  const float* gamma_o = (const float*)d_in[13];
  const float* beta_o  = (const float*)d_in[14];
  float* ws = (float*)d_ws;
  float* t0 = ws + OFF_X1;
  ushort* qt  = (ushort*)(ws + OFF_QT);
  ushort* kt  = (ushort*)(ws + OFF_KT);
  ushort* vbp = (ushort*)(ws + OFF_VB);
  float* yb = ws + OFF_SA;             // fallback sa
  ushort* ytp = (ushort*)(ws + OFF_YT);
  ushort* xbp = (ushort*)(ws + OFF_XB);
  float* acr = ws + OFF_AC;            // gram accumulator (zeroed by cvt)
  ushort* wbi = (ushort*)(ws + OFF_WBI);
  ushort* wbo = (ushort*)(ws + OFF_WBO);
  float* pt0 = ws + OFF_PT;
  float* pt1 = pt0 + 32;
  const ushort* zbuf = (const ushort*)(pt0 + 96);   // 16B of zeros (cvt zeroes pt[0..127])
  ushort* pacc = (ushort*)(ws + OFF_PO);
  float* pms  = ws + OFF_MS;
  float* outp = (float*)d_out;
  bool split = ws_size >= WS_NEED;

  cvt_k<<<1184, 256, 0, stream>>>(x, xbp, pt0, w_i, w_o, wbi, wbo, acr);

  conv_mfma_k<<<256, 512, 0, stream>>>(xbp, wbi, b_i, t0, pt0, zbuf);

  projgram_k<<<384, 256, 0, stream>>>(t0, pt0, gamma_i, beta_i,
                                      w_q, b_q, w_k, b_k, w_v, b_v, qt, kt, vbp, acr);

  if (split)
    flash_mfma_k<true><<<1024, 256, 0, stream>>>(qt, kt, vbp, yb, pacc, pms);
  else
    flash_mfma_k<false><<<256, 256, 0, stream>>>(qt, kt, vbp, yb, pacc, pms);

  if (split)
    ca_apply_k<4><<<256, 512, 0, stream>>>(t0, pt0, gamma_i, beta_i, acr, yb, pacc, pms, ytp);
  else
    ca_apply_k<1><<<256, 512, 0, stream>>>(t0, pt0, gamma_i, beta_i, acr, yb, pacc, pms, ytp);

  conv_mfma_k<<<256, 512, 0, stream>>>(ytp, wbo, b_o, t0, pt1, zbuf);
  gn_apply_k<<<1024, 256, 0, stream>>>(t0, pt1, gamma_o, beta_o, outp);
}

// Round 13
// 114.790 us; speedup vs baseline: 1.2521x; 1.0003x over previous
//
#include <hip/hip_runtime.h>

// workspace layout (float offsets)
#define OFF_X1  0            // raw conv out fp32 [b][c][n] (t0), 1M floats
#define OFF_SA  1048576      // fallback sa fp32, 1M floats
#define OFF_QT  2097152      // q bf16 [b][n][32] (1 MB)
#define OFF_KT  2359296      // k bf16 [b][n][32]
#define OFF_VB  2621440      // v bf16 [b][c][n] (2 MB)
#define OFF_YT  3145728      // y bf16 [b][n][ci] (2 MB)
#define OFF_XB  3670016      // x bf16 [b][n][ci] (2 MB)
#define OFF_AC  4194304      // gram accumulator fp32 [b][c][d] (64 KB, zeroed by cvt)
#define OFF_WBI 4210688
#define OFF_WBO 4265984
#define OFF_PT  4321280      // GN sums: pt0[32], pt1[32]; pt[96..103] = 16B zero pad for staging
#define OFF_PO  4325376      // split-flash acc partials bf16: 1024 x 4096 (8 MB)
#define OFF_MS  6422528      // split-flash (M,S): 1024 x 128 f32
#define WS_NEED ((size_t)6553600 * 4)

typedef __attribute__((ext_vector_type(8))) short short8v;
typedef __attribute__((ext_vector_type(4))) short short4v;
typedef __attribute__((ext_vector_type(4))) float f32x4;

__device__ __forceinline__ ushort f2bf(float f) {
  union { float f; unsigned u; } v; v.f = f;
  unsigned r = (v.u + 0x7fffu + ((v.u >> 16) & 1u)) >> 16;
  return (ushort)r;
}
__device__ __forceinline__ float bf2f(ushort u) {
  union { unsigned u; float f; } v; v.u = ((unsigned)u) << 16;
  return v.f;
}
__device__ __forceinline__ float max3f(float a, float b, float c) {
  return fmaxf(fmaxf(a, b), c);
}

// async 16B global->LDS (linear LDS dest = wave base + lane*16)
__device__ __forceinline__ void gld_lds16(const ushort* g, ushort* l) {
  __builtin_amdgcn_global_load_lds(
      (const __attribute__((address_space(1))) unsigned*)(unsigned long long)g,
      (__attribute__((address_space(3))) unsigned*)(unsigned long long)l,
      16, 0, 0);
}

// ---- merged converts: x transpose (0..255), weights (256..1119), zero ac+pt (1120..1183) ----
__global__ __launch_bounds__(256) void cvt_k(const float* __restrict__ x, ushort* __restrict__ xb,
    float* __restrict__ pt, const float* __restrict__ wi, const float* __restrict__ wo,
    ushort* __restrict__ wbi, ushort* __restrict__ wbo, float* __restrict__ acr) {
  __shared__ ushort tl[64 * 72];
  int blk = blockIdx.x;
  int t = threadIdx.x;
  if (blk < 256) {
    int b = blk >> 6;
    int n0 = (blk & 63) * 64;
    int ci = t >> 2, q = t & 3;
    const float* src = x + (size_t)(b * 64 + ci) * 4096 + n0 + q * 16;
    #pragma unroll
    for (int i = 0; i < 4; ++i) {
      float4 v = *reinterpret_cast<const float4*>(src + i * 4);
      tl[(q * 16 + i * 4 + 0) * 72 + ci] = f2bf(v.x);
      tl[(q * 16 + i * 4 + 1) * 72 + ci] = f2bf(v.y);
      tl[(q * 16 + i * 4 + 2) * 72 + ci] = f2bf(v.z);
      tl[(q * 16 + i * 4 + 3) * 72 + ci] = f2bf(v.w);
    }
    __syncthreads();
    int n = t >> 2, qq = t & 3;
    ushort* dst = xb + (size_t)(b * 4096 + n0 + n) * 64 + qq * 16;
    *reinterpret_cast<short8v*>(dst) = *reinterpret_cast<const short8v*>(&tl[n * 72 + qq * 16]);
    *reinterpret_cast<short8v*>(dst + 8) = *reinterpret_cast<const short8v*>(&tl[n * 72 + qq * 16 + 8]);
  } else if (blk < 1120) {
    int idx = (blk - 256) * 256 + t;       // 0 .. 221183
    const float* w = idx < 110592 ? wi : wo;
    ushort* wb = idx < 110592 ? wbi : wbo;
    int j = idx < 110592 ? idx : idx - 110592;
    int ci = j & 63, tap = (j >> 6) % 27, co = j / (64 * 27);
    wb[j] = f2bf(w[(co * 64 + ci) * 27 + tap]);
  } else {
    int idx = (blk - 1120) * 256 + t;      // 0 .. 16383
    acr[idx] = 0.f;
    if (blk == 1120 && t < 128) pt[t] = 0.f;   // stats [0..63] + zero pad [96..103]
  }
}

// ------- conv3d implicit GEMM (8 waves: 2 h-pairs x 4 co-groups) + GN-stats atomics -------
__global__ __launch_bounds__(512) void conv_mfma_k(const ushort* __restrict__ xt,
    const ushort* __restrict__ wb, const float* __restrict__ bias, float* __restrict__ out,
    float* __restrict__ ptg, const ushort* __restrict__ zbuf) {
  // chunk-linear tile: 2592 chunks of 16B (+32 pad) = [row(18)*18+w_s][c2]*8 ushorts
  __shared__ __align__(16) ushort xls[2624 * 8];
  __shared__ float sh_st[16];
  int blk = blockIdx.x;
  int h0 = (blk & 3) * 4;
  int d0 = (blk >> 2) & 15;
  int b  = blk >> 6;
  int tid = threadIdx.x;

  const ushort* xtb = xt + (size_t)b * 4096 * 64;
  {
    int wv0 = tid >> 6, ln = tid & 63;
    #pragma unroll
    for (int it = 0; it < 6; ++it) {
      int clbase;
      if (it < 5) clbase = (it * 8 + wv0) * 64;
      else { if (wv0 != 0) break; clbase = 2560; }
      int cl = clbase + ln;
      int c2 = cl & 7;
      int rw = cl >> 3;
      int w_s = rw % 18;
      int rowi = rw / 18;
      int dz = rowi / 6, h_s = rowi - dz * 6;
      int d = d0 + dz - 1, h = h0 + h_s - 1, w = w_s - 1;
      int csrc = c2 ^ (w_s & 7);
      const ushort* g = (d >= 0 && d < 16 && h >= 0 && h < 16 && w >= 0 && w < 16)
          ? xtb + (size_t)(d * 256 + h * 16 + w) * 64 + (csrc << 3)
          : zbuf;
      gld_lds16(g, xls + clbase * 8);
    }
  }
  __syncthreads();   // drains vmcnt for the LDS-direct loads

  int wv = tid >> 6, l = tid & 63;
  int wc4 = wv & 3, wn = wv >> 2;
  int lm = l & 15, lg = l >> 4;

  f32x4 acc[2] = {};
  const ushort* wbase = wb + (size_t)((wc4 * 16 + lm) * 1728) + lg * 8;

  #pragma unroll
  for (int s = 0; s < 54; ++s) {
    int tap = s >> 1, c0h = s & 1;
    int dz = tap / 9, dyx = tap - dz * 9;
    int dy = dyx / 3, dx = dyx - dy * 3;
    int wrow = lm + dx;
    int chunk = ((c0h * 4 + lg) ^ (wrow & 7)) << 3;
    int r0 = ((dz * 6 + wn * 2 + dy) * 18 + wrow) * 64 + chunk;
    short8v a0 = *reinterpret_cast<const short8v*>(&xls[r0]);
    short8v a1 = *reinterpret_cast<const short8v*>(&xls[r0 + 18 * 64]);
    short8v b0 = *reinterpret_cast<const short8v*>(wbase + s * 32);
    acc[0] = __builtin_amdgcn_mfma_f32_16x16x32_bf16(a0, b0, acc[0], 0, 0, 0);
    acc[1] = __builtin_amdgcn_mfma_f32_16x16x32_bf16(a1, b0, acc[1], 0, 0, 0);
  }

  float gs = 0.f, gss = 0.f;
  int co = wc4 * 16 + lm;
  float bs = bias[co];
  #pragma unroll
  for (int i = 0; i < 2; ++i) {
    int hh = h0 + wn * 2 + i;
    float4 o;
    o.x = acc[i][0] + bs; o.y = acc[i][1] + bs;
    o.z = acc[i][2] + bs; o.w = acc[i][3] + bs;
    gs  += o.x + o.y + o.z + o.w;
    gss = fmaf(o.x, o.x, gss); gss = fmaf(o.y, o.y, gss);
    gss = fmaf(o.z, o.z, gss); gss = fmaf(o.w, o.w, gss);
    *reinterpret_cast<float4*>(&out[(size_t)(b * 64 + co) * 4096 + d0 * 256 + hh * 16 + lg * 4]) = o;
  }
  #pragma unroll
  for (int off = 32; off > 0; off >>= 1) {
    gs  += __shfl_xor(gs, off);
    gss += __shfl_xor(gss, off);
  }
  if (l == 0) { sh_st[wv * 2] = gs; sh_st[wv * 2 + 1] = gss; }
  __syncthreads();
  if (tid < 8) {
    int g = tid >> 1, w2 = tid & 1;      // g = co-group = GN group
    float v = sh_st[g * 2 + w2] + sh_st[(4 + g) * 2 + w2];   // wn=0 (wv=g) + wn=1 (wv=4+g)
    atomicAdd(&ptg[(b * 4 + g) * 2 + w2], v);
  }
}

// ---------------- groupnorm apply + relu (final output), float4 ----------------
__global__ __launch_bounds__(256) void gn_apply_k(const float* __restrict__ t, const float* __restrict__ pt,
    const float* __restrict__ gamma, const float* __restrict__ beta, float* __restrict__ out) {
  int idx4 = blockIdx.x * 256 + threadIdx.x;     // 1024 blocks: 4 floats/thread
  int c = (idx4 >> 10) & 63, b = idx4 >> 16;
  int bg = b * 4 + (c >> 4);
  float s0 = pt[bg * 2], ss0 = pt[bg * 2 + 1];
  float m = s0 * (1.f / 65536.f);
  float r = rsqrtf(ss0 * (1.f / 65536.f) - m * m + 1e-5f);
  float ga = r * gamma[c], bb2 = beta[c] - m * r * gamma[c];
  float4 v = *reinterpret_cast<const float4*>(t + (size_t)idx4 * 4);
  float4 o;
  o.x = fmaxf(fmaf(v.x, ga, bb2), 0.f);
  o.y = fmaxf(fmaf(v.y, ga, bb2), 0.f);
  o.z = fmaxf(fmaf(v.z, ga, bb2), 0.f);
  o.w = fmaxf(fmaf(v.w, ga, bb2), 0.f);
  *reinterpret_cast<float4*>(out + (size_t)idx4 * 4) = o;
}

// ---------------- merged gram partial (blocks 0..127, dispatched first) + proj (128..383) ----------------
__global__ __launch_bounds__(256) void projgram_k(const float* __restrict__ t0, const float* __restrict__ pt0,
    const float* __restrict__ gamma, const float* __restrict__ beta,
    const float* __restrict__ wq, const float* __restrict__ bq,
    const float* __restrict__ wk, const float* __restrict__ bk,
    const float* __restrict__ wv_, const float* __restrict__ bv,
    ushort* __restrict__ qt, ushort* __restrict__ kt, ushort* __restrict__ vt,
    float* __restrict__ acr) {
  __shared__ __align__(16) float smem[64 * 68];
  int blk = blockIdx.x;
  int tid = threadIdx.x;
  if (blk >= 128) {
    // ---- projection (GN inline) ----
    float* xls = smem;
    int pblk = blk - 128;
    int b = pblk >> 6, n0 = (pblk & 63) * 64;
    {
      int ci = tid >> 2, q = tid & 3;
      int bg = b * 4 + (ci >> 4);
      float s0 = pt0[bg * 2], ss0 = pt0[bg * 2 + 1];
      float m = s0 * (1.f / 65536.f);
      float rv = rsqrtf(ss0 * (1.f / 65536.f) - m * m + 1e-5f);
      float ga = rv * gamma[ci], bb2 = beta[ci] - m * rv * gamma[ci];
      const float* src = t0 + (size_t)(b * 64 + ci) * 4096 + n0 + q * 16;
      #pragma unroll
      for (int i = 0; i < 4; ++i) {
        float4 v = *reinterpret_cast<const float4*>(src + i * 4);
        float* d = &xls[ci * 68 + q * 16 + i * 4];
        d[0] = fmaxf(fmaf(v.x, ga, bb2), 0.f);
        d[1] = fmaxf(fmaf(v.y, ga, bb2), 0.f);
        d[2] = fmaxf(fmaf(v.z, ga, bb2), 0.f);
        d[3] = fmaxf(fmaf(v.w, ga, bb2), 0.f);
      }
    }
    __syncthreads();
    int n = tid & 63, og = tid >> 6;
    float xr[64];
    #pragma unroll
    for (int c = 0; c < 64; ++c) xr[c] = xls[c * 68 + n];
    if (og < 2) {
      const float* w  = og == 0 ? wq : wk;
      const float* bb = og == 0 ? bq : bk;
      float scale = og == 0 ? 1.4426950408889634f : 1.0f;
      ushort* outp = og == 0 ? qt : kt;
      union { ushort u[16]; short8v v[2]; } pk;
      #pragma unroll
      for (int o = 0; o < 16; ++o) {
        const float* wr = w + o * 64;
        float acc = bb[o];
        #pragma unroll
        for (int c = 0; c < 64; ++c) acc = fmaf(wr[c], xr[c], acc);
        pk.u[o] = f2bf(acc * scale);
      }
      ushort* dst = outp + (size_t)(b * 4096 + n0 + n) * 32;
      *reinterpret_cast<short8v*>(dst) = pk.v[0];
      *reinterpret_cast<short8v*>(dst + 8) = pk.v[1];
      short8v z = {};
      *reinterpret_cast<short8v*>(dst + 16) = z;
      *reinterpret_cast<short8v*>(dst + 24) = z;
    } else {
      int o0 = (og - 2) * 32;
      #pragma unroll
      for (int o = 0; o < 32; ++o) {
        const float* wr = wv_ + (o0 + o) * 64;
        float acc = bv[o0 + o];
        #pragma unroll
        for (int c = 0; c < 64; ++c) acc = fmaf(wr[c], xr[c], acc);
        vt[(size_t)(b * 64 + o0 + o) * 4096 + n0 + n] = f2bf(acc);
      }
    }
  } else {
    // ---- gram partial (hi/lo bf16 MFMA, GN inline) -> atomicAdd into acr ----
    ushort* hi = (ushort*)smem;
    ushort* lo = hi + 4096;
    int gblk = blk;
    int b = gblk >> 5, ks = gblk & 31;
    int wv = tid >> 6, l = tid & 63, lm = l & 15, lg = l >> 4;
    int wr = wv >> 1, wd = wv & 1;
    f32x4 acc[2][2] = {};
    int sr = tid >> 2, sq = tid & 3;
    int bg = b * 4 + (sr >> 4);
    float s0p = pt0[bg * 2], ss0p = pt0[bg * 2 + 1];
    float mq = s0p * (1.f / 65536.f);
    float rq = rsqrtf(ss0p * (1.f / 65536.f) - mq * mq + 1e-5f);
    float ga = rq * gamma[sr], bb2 = beta[sr] - mq * rq * gamma[sr];
    const float* xb = t0 + (size_t)b * 262144;

    for (int kt2 = 0; kt2 < 2; ++kt2) {
      int n0 = ks * 128 + kt2 * 64;
      __syncthreads();
      const float* src = xb + (size_t)sr * 4096 + n0 + sq * 16;
      #pragma unroll
      for (int c2 = 0; c2 < 2; ++c2) {
        int chunk = sq * 2 + c2;
        int dchunk = chunk ^ (sr & 7);
        short8v hvv, lvv;
        #pragma unroll
        for (int j = 0; j < 8; ++j) {
          float v = fmaxf(fmaf(src[c2 * 8 + j], ga, bb2), 0.f);
          ushort hb = f2bf(v);
          union { float f; unsigned u; } uu; uu.u = ((unsigned)hb) << 16;
          hvv[j] = (short)hb;
          lvv[j] = (short)f2bf(v - uu.f);
        }
        *reinterpret_cast<short8v*>(hi + sr * 64 + dchunk * 8) = hvv;
        *reinterpret_cast<short8v*>(lo + sr * 64 + dchunk * 8) = lvv;
      }
      __syncthreads();
      __builtin_amdgcn_s_setprio(1);
      #pragma unroll
      for (int kk = 0; kk < 2; ++kk) {
        short8v ah[2], al[2], bh[2], bl[2];
        #pragma unroll
        for (int i = 0; i < 2; ++i) {
          int rc = wr * 32 + i * 16 + lm;
          int ca = ((kk * 4 + lg) ^ (rc & 7)) * 8;
          ah[i] = *reinterpret_cast<const short8v*>(hi + rc * 64 + ca);
          al[i] = *reinterpret_cast<const short8v*>(lo + rc * 64 + ca);
          int rd = wd * 32 + i * 16 + lm;
          int cb = ((kk * 4 + lg) ^ (rd & 7)) * 8;
          bh[i] = *reinterpret_cast<const short8v*>(hi + rd * 64 + cb);
          bl[i] = *reinterpret_cast<const short8v*>(lo + rd * 64 + cb);
        }
        #pragma unroll
        for (int i = 0; i < 2; ++i)
          #pragma unroll
          for (int j = 0; j < 2; ++j) {
            acc[i][j] = __builtin_amdgcn_mfma_f32_16x16x32_bf16(ah[i], bh[j], acc[i][j], 0, 0, 0);
            acc[i][j] = __builtin_amdgcn_mfma_f32_16x16x32_bf16(ah[i], bl[j], acc[i][j], 0, 0, 0);
            acc[i][j] = __builtin_amdgcn_mfma_f32_16x16x32_bf16(al[i], bh[j], acc[i][j], 0, 0, 0);
          }
      }
      __builtin_amdgcn_s_setprio(0);
    }
    float* acb = acr + (size_t)b * 4096;
    #pragma unroll
    for (int i = 0; i < 2; ++i)
      #pragma unroll
      for (int j = 0; j < 2; ++j)
        #pragma unroll
        for (int r = 0; r < 4; ++r) {
          int c = wr * 32 + i * 16 + lg * 4 + r;
          int d = wd * 32 + j * 16 + lm;
          atomicAdd(&acb[c * 64 + d], acc[i][j][r]);
        }
  }
}

// ---------------- flash spatial attention, bf16 MFMA, double-buffered, optional split-K ----------------
#define KP 40
#define VP 72
template<bool SPLIT>
__global__ __launch_bounds__(256) void flash_mfma_k(const ushort* __restrict__ qt,
    const ushort* __restrict__ kt, const ushort* __restrict__ vb, float* __restrict__ sa,
    ushort* __restrict__ pacc, float* __restrict__ pms) {
  __shared__ __align__(16) ushort kls[2][64 * KP];
  __shared__ __align__(16) ushort vls[2][64 * VP];
  __shared__ __align__(16) ushort pls[64 * VP];
  int s, mt, b;
  if (SPLIT) { s = blockIdx.x & 3; mt = (blockIdx.x >> 2) & 63; b = blockIdx.x >> 8; }
  else       { s = 0; mt = blockIdx.x & 63; b = blockIdx.x >> 6; }
  const int NT = SPLIT ? 16 : 64;
  int m0 = mt * 64;
  int kofs = s * 1024;
  int tid = threadIdx.x;
  int w = tid >> 6, l = tid & 63;
  int lm = l & 15, lg = l >> 4;

  short8v qf = *reinterpret_cast<const short8v*>(
      qt + (size_t)(b * 4096 + m0 + w * 16 + lm) * 32 + lg * 8);

  f32x4 acc[4] = {};
  float M = -1e30f, S = 0.f;

  int sr = tid >> 2, sq = tid & 3;
  const ushort* ksrc = kt + (size_t)b * 4096 * 32 + (size_t)kofs * 32 + (size_t)sr * 32 + sq * 8;
  const ushort* vsrc = vb + (size_t)b * 64 * 4096 + (size_t)sr * 4096 + kofs + sq * 16;
  int koff = sr * KP + sq * 8;
  int voff = sr * VP + sq * 16;

  {
    short8v kr = *reinterpret_cast<const short8v*>(ksrc);
    short8v v0 = *reinterpret_cast<const short8v*>(vsrc);
    short8v v1 = *reinterpret_cast<const short8v*>(vsrc + 8);
    *reinterpret_cast<short8v*>(&kls[0][koff]) = kr;
    *reinterpret_cast<short8v*>(&vls[0][voff]) = v0;
    *reinterpret_cast<short8v*>(&vls[0][voff + 8]) = v1;
  }

  ushort* plb = &pls[(w * 16 + lm) * VP];

  #pragma unroll 2
  for (int it = 0; it < NT; ++it) {
    int cur = it & 1;
    int nx = it < NT - 1 ? it + 1 : NT - 1;
    short8v knr = *reinterpret_cast<const short8v*>(ksrc + (size_t)nx * 2048);
    short8v vn0 = *reinterpret_cast<const short8v*>(vsrc + nx * 64);
    short8v vn1 = *reinterpret_cast<const short8v*>(vsrc + nx * 64 + 8);

    __syncthreads();

    const ushort* kb  = &kls[cur][0];
    const ushort* vbk = &vls[cur][0];

    f32x4 sf[4];
    __builtin_amdgcn_s_setprio(1);
    #pragma unroll
    for (int nt = 0; nt < 4; ++nt) {
      short8v kf = *reinterpret_cast<const short8v*>(&kb[(nt * 16 + lm) * KP + lg * 8]);
      f32x4 z = {};
      sf[nt] = __builtin_amdgcn_mfma_f32_16x16x32_bf16(kf, qf, z, 0, 0, 0);
    }
    __builtin_amdgcn_s_setprio(0);

    float t0_ = max3f(sf[0][0], sf[0][1], sf[0][2]);
    float t1_ = max3f(sf[0][3], sf[1][0], sf[1][1]);
    float t2_ = max3f(sf[1][2], sf[1][3], sf[2][0]);
    float t3_ = max3f(sf[2][1], sf[2][2], sf[2][3]);
    float t4_ = max3f(sf[3][0], sf[3][1], sf[3][2]);
    float tmax = fmaxf(max3f(t0_, t1_, t2_), max3f(t3_, t4_, sf[3][3]));
    tmax = fmaxf(tmax, __shfl_xor(tmax, 16));
    tmax = fmaxf(tmax, __shfl_xor(tmax, 32));
    if (!__all(tmax <= M)) {
      float Mn = fmaxf(M, tmax);
      float sc = __builtin_amdgcn_exp2f(M - Mn);
      M = Mn;
      S *= sc;
      #pragma unroll
      for (int ct = 0; ct < 4; ++ct)
        #pragma unroll
        for (int r = 0; r < 4; ++r) acc[ct][r] *= sc;
    }
    float tsum = 0.f;
    float p[16];
    #pragma unroll
    for (int nt = 0; nt < 4; ++nt)
      #pragma unroll
      for (int r = 0; r < 4; ++r) {
        float e = __builtin_amdgcn_exp2f(sf[nt][r] - M);
        p[nt * 4 + r] = e;
        tsum += e;
      }
    tsum += __shfl_xor(tsum, 16);
    tsum += __shfl_xor(tsum, 32);
    S += tsum;

    #pragma unroll
    for (int nt = 0; nt < 4; ++nt) {
      unsigned p01, p23;
      asm("v_cvt_pk_bf16_f32 %0, %1, %2" : "=v"(p01) : "v"(p[nt * 4 + 0]), "v"(p[nt * 4 + 1]));
      asm("v_cvt_pk_bf16_f32 %0, %1, %2" : "=v"(p23) : "v"(p[nt * 4 + 2]), "v"(p[nt * 4 + 3]));
      union { unsigned u[2]; short4v v; } pk;
      pk.u[0] = p01; pk.u[1] = p23;
      *reinterpret_cast<short4v*>(plb + nt * 16 + lg * 4) = pk.v;
    }
    asm volatile("s_waitcnt lgkmcnt(0)" ::: "memory");
    __builtin_amdgcn_sched_barrier(0);

    __builtin_amdgcn_s_setprio(1);
    #pragma unroll
    for (int nh = 0; nh < 2; ++nh) {
      short8v pf = *reinterpret_cast<const short8v*>(plb + nh * 32 + lg * 8);
      #pragma unroll
      for (int ct = 0; ct < 4; ++ct) {
        short8v vf = *reinterpret_cast<const short8v*>(&vbk[(ct * 16 + lm) * VP + nh * 32 + lg * 8]);
        acc[ct] = __builtin_amdgcn_mfma_f32_16x16x32_bf16(vf, pf, acc[ct], 0, 0, 0);
      }
    }
    __builtin_amdgcn_s_setprio(0);

    if (it < NT - 1) {
      *reinterpret_cast<short8v*>(&kls[cur ^ 1][koff]) = knr;
      *reinterpret_cast<short8v*>(&vls[cur ^ 1][voff]) = vn0;
      *reinterpret_cast<short8v*>(&vls[cur ^ 1][voff + 8]) = vn1;
    }
  }

  if (SPLIT) {
    int blk2 = (b * 64 + mt) * 4 + s;
    ushort* pa = pacc + (size_t)blk2 * 4096;
    #pragma unroll
    for (int ct = 0; ct < 4; ++ct)
      #pragma unroll
      for (int r = 0; r < 4; ++r)
        pa[(ct * 16 + lg * 4 + r) * 64 + w * 16 + lm] = f2bf(acc[ct][r]);
    if (l < 16) {
      pms[(size_t)blk2 * 128 + (w * 16 + lm) * 2]     = M;
      pms[(size_t)blk2 * 128 + (w * 16 + lm) * 2 + 1] = S;
    }
  } else {
    float inv = 1.f / S;
    #pragma unroll
    for (int ct = 0; ct < 4; ++ct)
      #pragma unroll
      for (int r = 0; r < 4; ++r)
        sa[(size_t)(b * 64 + ct * 16 + lg * 4 + r) * 4096 + m0 + w * 16 + lm] = acc[ct][r] * inv;
  }
}

// ------- y = x1 + sa(+combine) + softmax(gram) @ x1 -> bf16 [b][n][ci]; 8 waves -------
template<int NSPLIT>
__global__ __launch_bounds__(512) void ca_apply_k(const float* __restrict__ t0,
    const float* __restrict__ pt0, const float* __restrict__ gamma, const float* __restrict__ beta,
    const float* __restrict__ acr, const float* __restrict__ sa,
    const ushort* __restrict__ pacc, const float* __restrict__ pms, ushort* __restrict__ yt) {
  __shared__ float x1f[64 * 72];
  __shared__ float acf[64 * 72];
  __shared__ float wls[4 * 64];
  int b = blockIdx.x >> 6, mt = blockIdx.x & 63;
  int n0 = mt * 64;
  int tid = threadIdx.x;
  {
    int d = tid >> 3, q = tid & 7;     // 8 cols per thread
    int bg = b * 4 + (d >> 4);
    float s0p = pt0[bg * 2], ss0p = pt0[bg * 2 + 1];
    float mq = s0p * (1.f / 65536.f);
    float rq = rsqrtf(ss0p * (1.f / 65536.f) - mq * mq + 1e-5f);
    float ga = rq * gamma[d], bb2 = beta[d] - mq * rq * gamma[d];
    const float* xs = t0 + (size_t)(b * 64 + d) * 4096 + n0 + q * 8;
    const float* as = acr + (size_t)(b * 64 + d) * 64 + q * 8;
    #pragma unroll
    for (int i = 0; i < 2; ++i) {
      float4 v = *reinterpret_cast<const float4*>(xs + i * 4);
      x1f[d * 72 + q * 8 + i * 4 + 0] = fmaxf(fmaf(v.x, ga, bb2), 0.f);
      x1f[d * 72 + q * 8 + i * 4 + 1] = fmaxf(fmaf(v.y, ga, bb2), 0.f);
      x1f[d * 72 + q * 8 + i * 4 + 2] = fmaxf(fmaf(v.z, ga, bb2), 0.f);
      x1f[d * 72 + q * 8 + i * 4 + 3] = fmaxf(fmaf(v.w, ga, bb2), 0.f);
      float4 a = *reinterpret_cast<const float4*>(as + i * 4);
      acf[d * 72 + q * 8 + i * 4 + 0] = a.x;
      acf[d * 72 + q * 8 + i * 4 + 1] = a.y;
      acf[d * 72 + q * 8 + i * 4 + 2] = a.z;
      acf[d * 72 + q * 8 + i * 4 + 3] = a.w;
    }
  }
  if (NSPLIT > 1 && tid < 64) {
    int m = tid;
    size_t msb = (size_t)(b * 64 + mt) * NSPLIT * 128;
    float Ms[NSPLIT], Ss[NSPLIT];
    float Mg = -1e30f;
    #pragma unroll
    for (int s = 0; s < NSPLIT; ++s) {
      Ms[s] = pms[msb + s * 128 + m * 2];
      Ss[s] = pms[msb + s * 128 + m * 2 + 1];
      Mg = fmaxf(Mg, Ms[s]);
    }
    float Stot = 0.f;
    #pragma unroll
    for (int s = 0; s < NSPLIT; ++s) {
      float wv = __builtin_amdgcn_exp2f(Ms[s] - Mg);
      wls[s * 64 + m] = wv;
      Stot += wv * Ss[s];
    }
    float inv = 1.f / Stot;
    #pragma unroll
    for (int s = 0; s < NSPLIT; ++s) wls[s * 64 + m] *= inv;
  }
  __syncthreads();
  // in-place row softmax of acf (rows = c, over d); 8 threads/row
  {
    int r = tid >> 3, q4 = tid & 7;
    float* row = &acf[r * 72 + q4 * 8];
    float mx = -1e30f;
    #pragma unroll
    for (int i = 0; i < 8; ++i) mx = fmaxf(mx, row[i]);
    mx = fmaxf(mx, __shfl_xor(mx, 1));
    mx = fmaxf(mx, __shfl_xor(mx, 2));
    mx = fmaxf(mx, __shfl_xor(mx, 4));
    float e[8];
    float sum = 0.f;
    #pragma unroll
    for (int i = 0; i < 8; ++i) { e[i] = __expf(row[i] - mx); sum += e[i]; }
    sum += __shfl_xor(sum, 1);
    sum += __shfl_xor(sum, 2);
    sum += __shfl_xor(sum, 4);
    float inv = 1.f / sum;
    #pragma unroll
    for (int i = 0; i < 8; ++i) row[i] = e[i] * inv;
  }
  __syncthreads();
  int m = tid & 63, cg = tid >> 6;    // 8 waves: 8 channels each
  float sval[8];
  if (NSPLIT > 1) {
    #pragma unroll
    for (int ci = 0; ci < 8; ++ci) sval[ci] = 0.f;
    const ushort* pb = pacc + (size_t)(b * 64 + mt) * NSPLIT * 4096;
    #pragma unroll
    for (int s = 0; s < NSPLIT; ++s) {
      float wv = wls[s * 64 + m];
      #pragma unroll
      for (int ci = 0; ci < 8; ++ci)
        sval[ci] = fmaf(wv, bf2f(pb[s * 4096 + (cg * 8 + ci) * 64 + m]), sval[ci]);
    }
  } else {
    #pragma unroll
    for (int ci = 0; ci < 8; ++ci)
      sval[ci] = sa[(size_t)(b * 64 + cg * 8 + ci) * 4096 + n0 + m];
  }
  float xcol[64];
  #pragma unroll
  for (int d = 0; d < 64; ++d) xcol[d] = x1f[d * 72 + m];
  union { ushort u[8]; short8v v; } pk;
  #pragma unroll
  for (int ci = 0; ci < 8; ++ci) {
    int c = cg * 8 + ci;
    float o = xcol[c] + sval[ci];
    const float* ar = &acf[c * 72];
    #pragma unroll
    for (int d4 = 0; d4 < 16; ++d4) {
      float4 a4 = *reinterpret_cast<const float4*>(ar + d4 * 4);
      o = fmaf(a4.x, xcol[d4 * 4 + 0], o);
      o = fmaf(a4.y, xcol[d4 * 4 + 1], o);
      o = fmaf(a4.z, xcol[d4 * 4 + 2], o);
      o = fmaf(a4.w, xcol[d4 * 4 + 3], o);
    }
    pk.u[ci] = f2bf(o);
  }
  ushort* dst = yt + (size_t)(b * 4096 + n0 + m) * 64 + cg * 8;
  *reinterpret_cast<short8v*>(dst) = pk.v;
}

extern "C" void kernel_launch(void* const* d_in, const int* in_sizes, int n_in,
                              void* d_out, int out_size, void* d_ws, size_t ws_size,
                              hipStream_t stream) {
  const float* x       = (const float*)d_in[0];
  const float* w_i     = (const float*)d_in[1];
  const float* b_i     = (const float*)d_in[2];
  const float* gamma_i = (const float*)d_in[3];
  const float* beta_i  = (const float*)d_in[4];
  const float* w_q     = (const float*)d_in[5];
  const float* b_q     = (const float*)d_in[6];
  const float* w_k     = (const float*)d_in[7];
  const float* b_k     = (const float*)d_in[8];
  const float* w_v     = (const float*)d_in[9];
  const float* b_v     = (const float*)d_in[10];
  const float* w_o     = (const float*)d_in[11];
  const float* b_o     = (const float*)d_in[12];
  const float* gamma_o = (const float*)d_in[13];
  const float* beta_o  = (const float*)d_in[14];
  float* ws = (float*)d_ws;
  float* t0 = ws + OFF_X1;
  ushort* qt  = (ushort*)(ws + OFF_QT);
  ushort* kt  = (ushort*)(ws + OFF_KT);
  ushort* vbp = (ushort*)(ws + OFF_VB);
  float* yb = ws + OFF_SA;             // fallback sa
  ushort* ytp = (ushort*)(ws + OFF_YT);
  ushort* xbp = (ushort*)(ws + OFF_XB);
  float* acr = ws + OFF_AC;            // gram accumulator (zeroed by cvt)
  ushort* wbi = (ushort*)(ws + OFF_WBI);
  ushort* wbo = (ushort*)(ws + OFF_WBO);
  float* pt0 = ws + OFF_PT;
  float* pt1 = pt0 + 32;
  const ushort* zbuf = (const ushort*)(pt0 + 96);   // 16B of zeros (cvt zeroes pt[0..127])
  ushort* pacc = (ushort*)(ws + OFF_PO);
  float* pms  = ws + OFF_MS;
  float* outp = (float*)d_out;
  bool split = ws_size >= WS_NEED;

  cvt_k<<<1184, 256, 0, stream>>>(x, xbp, pt0, w_i, w_o, wbi, wbo, acr);

  conv_mfma_k<<<256, 512, 0, stream>>>(xbp, wbi, b_i, t0, pt0, zbuf);

  projgram_k<<<384, 256, 0, stream>>>(t0, pt0, gamma_i, beta_i,
                                      w_q, b_q, w_k, b_k, w_v, b_v, qt, kt, vbp, acr);

  if (split)
    flash_mfma_k<true><<<1024, 256, 0, stream>>>(qt, kt, vbp, yb, pacc, pms);
  else
    flash_mfma_k<false><<<256, 256, 0, stream>>>(qt, kt, vbp, yb, pacc, pms);

  if (split)
    ca_apply_k<4><<<256, 512, 0, stream>>>(t0, pt0, gamma_i, beta_i, acr, yb, pacc, pms, ytp);
  else
    ca_apply_k<1><<<256, 512, 0, stream>>>(t0, pt0, gamma_i, beta_i, acr, yb, pacc, pms, ytp);

  conv_mfma_k<<<256, 512, 0, stream>>>(ytp, wbo, b_o, t0, pt1, zbuf);
  gn_apply_k<<<1024, 256, 0, stream>>>(t0, pt1, gamma_o, beta_o, outp);
}